// Round 6
// baseline (4786.848 us; speedup 1.0000x reference)
//
#include <hip/hip_runtime.h>
#include <hip/hip_cooperative_groups.h>
#include <cmath>

typedef __bf16 bf16x8 __attribute__((ext_vector_type(8)));
typedef float floatx4 __attribute__((ext_vector_type(4)));
typedef unsigned ux4 __attribute__((ext_vector_type(4)));
typedef unsigned short u16;

#define B_ 16
#define T_ 512
#define D_ 512
#define H_ 1024
#define G_ 2048  // 2H
#define BH (B_ * H_)
#define HP 1034  // pitch u16: 2068 B = 517 dw, odd -> 16 rows hit 16 distinct bank
                 // groups; max 2-way aliasing across (am,kq) = free (m136).
                 // 4B-aligned b128/uint2 LDS ops validated correct in R5.

// ---------------- cast fp32 -> bf16 (RNE) ----------------
__global__ void cast_f32_bf16(const float* __restrict__ src, u16* __restrict__ dst, int n) {
  int i = blockIdx.x * blockDim.x + threadIdx.x;
  int stride = gridDim.x * blockDim.x;
  for (; i < n; i += stride) {
    __bf16 b = (__bf16)src[i];
    dst[i] = *reinterpret_cast<u16*>(&b);
  }
}

// ---------------- w = x @ W^T  (bf16 MFMA, fp32 out), layout w[t][b][2H] ----------------
__launch_bounds__(256, 1)
__global__ void gemm_xW(const u16* __restrict__ xb, const u16* __restrict__ Wb,
                        float* __restrict__ w) {
  const int lane = threadIdx.x & 63;
  const int wv = threadIdx.x >> 6;
  const int rt0 = blockIdx.x * 16;
  const int bidx = rt0 >> 9;
  const int t0 = rt0 & 511;
  const int am = lane & 15;
  const int kq = lane >> 4;

  bf16x8 af[16];
  {
    const u16* xrow = xb + (size_t)(rt0 + am) * D_ + kq * 8;
#pragma unroll
    for (int kk = 0; kk < 16; ++kk)
      af[kk] = *reinterpret_cast<const bf16x8*>(xrow + kk * 32);
  }

#pragma unroll 1
  for (int nt = 0; nt < 32; ++nt) {
    const int n0 = wv * 512 + nt * 16;
    floatx4 acc = {0.f, 0.f, 0.f, 0.f};
    const u16* wrow = Wb + (size_t)(n0 + am) * D_ + kq * 8;
#pragma unroll
    for (int kk = 0; kk < 16; ++kk) {
      bf16x8 bfr = *reinterpret_cast<const bf16x8*>(wrow + kk * 32);
      acc = __builtin_amdgcn_mfma_f32_16x16x32_bf16(af[kk], bfr, acc, 0, 0, 0);
    }
#pragma unroll
    for (int i = 0; i < 4; ++i) {
      int m = kq * 4 + i;
      w[(size_t)((t0 + m) * 16 + bidx) * G_ + n0 + am] = acc[i];
    }
  }
}

// ---------------- in-place LayerNorm over rows of 2048 ----------------
__launch_bounds__(256, 1)
__global__ void layernorm_rows(float* __restrict__ w, const float* __restrict__ gamma,
                               const float* __restrict__ beta) {
  float* r = w + (size_t)blockIdx.x * G_;
  float v[8];
  float s = 0.f, ss = 0.f;
#pragma unroll
  for (int i = 0; i < 8; ++i) {
    v[i] = r[threadIdx.x + i * 256];
    s += v[i];
    ss += v[i] * v[i];
  }
#pragma unroll
  for (int d = 1; d < 64; d <<= 1) {
    s += __shfl_xor(s, d, 64);
    ss += __shfl_xor(ss, d, 64);
  }
  __shared__ float ls[4], lss[4];
  const int wv = threadIdx.x >> 6;
  if ((threadIdx.x & 63) == 0) { ls[wv] = s; lss[wv] = ss; }
  __syncthreads();
  float S = ls[0] + ls[1] + ls[2] + ls[3];
  float SS = lss[0] + lss[1] + lss[2] + lss[3];
  float mu = S * (1.f / 2048.f);
  float var = SS * (1.f / 2048.f) - mu * mu;
  float rs = rsqrtf(var + 1e-5f);
#pragma unroll
  for (int i = 0; i < 8; ++i) {
    int g = threadIdx.x + i * 256;
    r[g] = (v[i] - mu) * rs * gamma[g] + beta[g];
  }
}

// ---------------- persistent LiGRU scan: role split + single-XCD + sc0 loads ------
// R2->R5 established three independent per-phase poisons; this round removes all 3
// simultaneously (first time):
//  (1) store-ack wait: ROLE SPLIT (R4-validated). Waves 0-3 = updaters (publish
//      sc0sc1 tagged stores, never wait vmcnt). Waves 4-7 = loaders (poll + stage,
//      never store to global).
//  (2) load RT: XCD ELECTION (R3-validated) puts all 32 workers on ONE XCD; the
//      speculative bundle polls use sc0 -> served by the shared local L2 (~0.25us,
//      R3 FETCH evidence), not the ~0.9us system path (R5 FETCH arithmetic).
//      Escalation net: 1 sc0 retry, then acquire(agent) fence + sc0sc1 (R3-proven).
//  (3) LDS bank conflicts: HP=1034 odd-dword pitch (R5-validated mechanism).
// Plus: w nt-loads issued at phase START one phase ahead, retired by a counted
// vmcnt(1) so their HBM latency gets a full phase of flight.
__launch_bounds__(512, 1)
__global__ void ligru_scan(const float* __restrict__ w, const u16* __restrict__ Ub,
                           const float* __restrict__ h0, float* __restrict__ out,
                           unsigned* __restrict__ hbuf, unsigned* __restrict__ elect) {
  // ---- election: claim a slot on my XCD; first XCD to 32 slots wins ----
  __shared__ unsigned s_role;
  if (threadIdx.x == 0) {
    unsigned xcc;
    asm volatile("s_getreg_b32 %0, hwreg(HW_REG_XCC_ID)" : "=s"(xcc));
    xcc &= 7u;
    unsigned ticket = atomicAdd(&elect[xcc], 1u);
    if (ticket == 31u) atomicCAS(&elect[8], 0u, xcc + 1u);
    unsigned wn;
    while ((wn = atomicAdd(&elect[8], 0u)) == 0u) __builtin_amdgcn_s_sleep(8);
    s_role = (wn == xcc + 1u && ticket < 32u) ? ticket : 0xFFFFFFFFu;
  }
  __syncthreads();
  const unsigned role = s_role;
  if (role == 0xFFFFFFFFu) return;  // not a worker

  const int tid = threadIdx.x;
  const int lane = tid & 63;
  const int wv = tid >> 6;
  const int am = lane & 15;
  const int kq = lane >> 4;
  const int j0 = (int)role * 32;
  const bool loader = (tid >= 256);
  const int jt = wv & 3;   // tile 0..3
  const int kh = wv >> 2;  // 0 = updater waves, 1 = loader waves

  __shared__ u16 lds_h[16 * HP];         // rows g*8..g*8+7 = group g h (bf16 bits)
  __shared__ float lds_r[4][2][16][16];  // [tile][K-half][m-row][n-col] partials
  __shared__ float lds_w[2][8][2][32];   // [group][batch][gate][col] staged w_t

  const int grow = (am < 8) ? (j0 + 8 * jt + am) : (H_ + j0 + 8 * jt + (am - 8));

  // U fragments: 16 gate-rows x K=512 half, register resident
  bf16x8 uf[16];
  {
    const u16* urow = Ub + (size_t)grow * H_ + kh * 512 + kq * 8;
#pragma unroll
    for (int kk = 0; kk < 16; ++kk)
      uf[kk] = *reinterpret_cast<const bf16x8*>(urow + kk * 32);
  }

  // updater mapping: thread owns (batch bl of each group, col jj)
  const int bl = tid >> 5;   // 0..7 for updaters
  const int jj = tid & 31;
  const int col = j0 + jj;
  float hreg0 = 0.f, hreg1 = 0.f;

  // loader mapping
  const int li = tid & 255;        // 0..255
  const int wb = li >> 5;          // w batch-local
  const int wgt = (li >> 4) & 1;   // w gate
  const int wc2 = (li & 15) * 2;   // w col pair
  ux4 chv0, chv1, chv2, chv3, chv4, chv5, chv6, chv7;
  uint2 wnx0, wnx1;                // w ping-pong: wnx0 for G=0 phases, wnx1 for G=1

#define LOADB(SCSTR, cb)                                                          \
  asm volatile("global_load_dwordx4 %0, %8, off " SCSTR "\n\t"                    \
               "global_load_dwordx4 %1, %9, off " SCSTR "\n\t"                    \
               "global_load_dwordx4 %2, %10, off " SCSTR "\n\t"                   \
               "global_load_dwordx4 %3, %11, off " SCSTR "\n\t"                   \
               "global_load_dwordx4 %4, %12, off " SCSTR "\n\t"                   \
               "global_load_dwordx4 %5, %13, off " SCSTR "\n\t"                   \
               "global_load_dwordx4 %6, %14, off " SCSTR "\n\t"                   \
               "global_load_dwordx4 %7, %15, off " SCSTR                          \
               : "=&v"(chv0), "=&v"(chv1), "=&v"(chv2), "=&v"(chv3),              \
                 "=&v"(chv4), "=&v"(chv5), "=&v"(chv6), "=&v"(chv7)               \
               : "v"(cb), "v"((cb) + 1024), "v"((cb) + 2048), "v"((cb) + 3072),   \
                 "v"((cb) + 4096), "v"((cb) + 5120), "v"((cb) + 6144),            \
                 "v"((cb) + 7168)                                                 \
               : "memory")

#define TAGCHK(tg)                                                                \
  ((((chv0.x ^ (tg)) | (chv0.y ^ (tg)) | (chv0.z ^ (tg)) | (chv0.w ^ (tg)) |      \
     (chv1.x ^ (tg)) | (chv1.y ^ (tg)) | (chv1.z ^ (tg)) | (chv1.w ^ (tg)) |      \
     (chv2.x ^ (tg)) | (chv2.y ^ (tg)) | (chv2.z ^ (tg)) | (chv2.w ^ (tg)) |      \
     (chv3.x ^ (tg)) | (chv3.y ^ (tg)) | (chv3.z ^ (tg)) | (chv3.w ^ (tg)) |      \
     (chv4.x ^ (tg)) | (chv4.y ^ (tg)) | (chv4.z ^ (tg)) | (chv4.w ^ (tg)) |      \
     (chv5.x ^ (tg)) | (chv5.y ^ (tg)) | (chv5.z ^ (tg)) | (chv5.w ^ (tg)) |      \
     (chv6.x ^ (tg)) | (chv6.y ^ (tg)) | (chv6.z ^ (tg)) | (chv6.w ^ (tg)) |      \
     (chv7.x ^ (tg)) | (chv7.y ^ (tg)) | (chv7.z ^ (tg)) | (chv7.w ^ (tg))) &     \
    0xFFFFu))

#define UNPACK_ROW(C, GG)                                                         \
  {                                                                               \
    unsigned lo = (chv##C.x >> 16) | (chv##C.y & 0xFFFF0000u);                    \
    unsigned hi = (chv##C.z >> 16) | (chv##C.w & 0xFFFF0000u);                    \
    uint2 pk2; pk2.x = lo; pk2.y = hi;                                            \
    *reinterpret_cast<uint2*>(&lds_h[((GG) * 8 + (C)) * HP + 4 * li]) = pk2;      \
  }

#define ISSUE_W(DST, trow)                                                        \
  {                                                                               \
    const float* ws_ = w + (size_t)(trow) * G_ + wgt * H_ + j0 + wc2;             \
    asm volatile("global_load_dwordx2 %0, %1, off nt"                             \
                 : "=&v"(DST) : "v"(ws_) : "memory");                             \
  }

  // ---- init ----
  if (!loader) {
    hreg0 = h0[col];
    hreg1 = hreg0;
    __bf16 hb = (__bf16)hreg0;
    unsigned pk = ((unsigned)*reinterpret_cast<u16*>(&hb) << 16) | 1u;
    unsigned* p0 = hbuf + (0 * 8 + bl) * H_ + col;
    unsigned* p1 = hbuf + (8 + bl) * H_ + col;
    asm volatile("global_store_dword %0, %2, off sc0 sc1\n\t"
                 "global_store_dword %1, %2, off sc0 sc1"
                 :: "v"(p0), "v"(p1), "v"(pk) : "memory");
  } else {
    // W(t=0, group 0) into wnx0, then bundle(t=0, group 0): issue order matters
    // for the counted vmcnt below (oldest = w, then 8 bundle chunks).
    ISSUE_W(wnx0, 0 * 16 + 0 * 8 + wb);
    const unsigned* nb = hbuf + 4 * li;
    LOADB("sc0", nb);
  }

#define PHASE(GG, HREG, WCUR, WNXT)                                               \
  {                                                                               \
    const unsigned tag = (unsigned)(t + 1);                                       \
    const int tn = (GG == 0) ? t : ((t + 1 < T_) ? (t + 1) : t);                  \
    const int gn = GG ^ 1;                                                        \
    if (loader) {                                                                 \
      /* issue NEXT phase's w first (full phase of flight before its wait) */     \
      ISSUE_W(WNXT, tn * 16 + gn * 8 + wb);                                       \
      /* counted wait: retires w_cur + bundle_cur (9 oldest), leaves w_next */    \
      asm volatile("s_waitcnt vmcnt(1)"                                           \
                   : "+v"(chv0), "+v"(chv1), "+v"(chv2), "+v"(chv3),              \
                     "+v"(chv4), "+v"(chv5), "+v"(chv6), "+v"(chv7),              \
                     "+v"(WCUR) :: "memory");                                     \
      __builtin_amdgcn_sched_barrier(0);                                          \
      unsigned bad = TAGCHK(tag);                                                 \
      if (bad) {                                                                  \
        const unsigned* cb = hbuf + (size_t)(t & 1) * BH + (GG) * 8192 + 4 * li;  \
        unsigned rounds = 0;                                                      \
        do {                                                                      \
          if (rounds == 0) {                                                      \
            LOADB("sc0", cb);                                                     \
          } else {                                                                \
            __builtin_amdgcn_fence(__ATOMIC_ACQUIRE, "agent");                    \
            LOADB("sc0 sc1", cb);                                                 \
          }                                                                       \
          asm volatile("s_waitcnt vmcnt(0)"                                       \
                       : "+v"(chv0), "+v"(chv1), "+v"(chv2), "+v"(chv3),          \
                         "+v"(chv4), "+v"(chv5), "+v"(chv6), "+v"(chv7)           \
                       :: "memory");                                              \
          bad = TAGCHK(tag);                                                      \
        } while (bad && ++rounds < 4096u);                                        \
      }                                                                           \
      UNPACK_ROW(0, GG) UNPACK_ROW(1, GG) UNPACK_ROW(2, GG) UNPACK_ROW(3, GG)     \
      UNPACK_ROW(4, GG) UNPACK_ROW(5, GG) UNPACK_ROW(6, GG) UNPACK_ROW(7, GG)     \
      *reinterpret_cast<uint2*>(&lds_w[GG][wb][wgt][wc2]) = WCUR;                 \
      asm volatile("s_waitcnt lgkmcnt(0)" ::: "memory");                          \
    }                                                                             \
    __builtin_amdgcn_s_barrier(); /* (A) staging complete */                      \
    __builtin_amdgcn_sched_barrier(0);                                            \
    floatx4 acc0 = {0, 0, 0, 0}, acc1 = {0, 0, 0, 0};                             \
    {                                                                             \
      const u16* hb = &lds_h[am * HP + kh * 512 + kq * 8];                        \
      _Pragma("unroll")                                                           \
      for (int kk = 0; kk < 8; ++kk) {                                            \
        bf16x8 x0 = *reinterpret_cast<const bf16x8*>(hb + (kk + 0) * 32);         \
        bf16x8 x1 = *reinterpret_cast<const bf16x8*>(hb + (kk + 8) * 32);         \
        acc0 = __builtin_amdgcn_mfma_f32_16x16x32_bf16(x0, uf[kk + 0], acc0, 0, 0, 0); \
        acc1 = __builtin_amdgcn_mfma_f32_16x16x32_bf16(x1, uf[kk + 8], acc1, 0, 0, 0); \
      }                                                                           \
    }                                                                             \
    floatx4 acc = acc0 + acc1;                                                    \
    _Pragma("unroll")                                                             \
    for (int i = 0; i < 4; ++i)                                                   \
      lds_r[jt][kh][kq * 4 + i][am] = acc[i];                                     \
    asm volatile("s_waitcnt lgkmcnt(0)" ::: "memory");                            \
    __builtin_amdgcn_s_barrier(); /* (B) partials complete */                     \
    __builtin_amdgcn_sched_barrier(0);                                            \
    if (loader) {                                                                 \
      /* speculative bundle for NEXT phase (sc0: local-XCD L2 path) */            \
      const unsigned* nb = hbuf + (size_t)(tn & 1) * BH + gn * 8192 + 4 * li;     \
      LOADB("sc0", nb);                                                           \
    } else {                                                                      \
      const int tl = jj >> 3, cc = jj & 7;                                        \
      const int mr = (GG) * 8 + bl;                                               \
      float a = lds_r[tl][0][mr][cc] + lds_r[tl][1][mr][cc] +                     \
                lds_w[GG][bl][0][jj];                                             \
      float z = lds_r[tl][0][mr][8 + cc] + lds_r[tl][1][mr][8 + cc] +             \
                lds_w[GG][bl][1][jj];                                             \
      float zs = 1.f / (1.f + __expf(-z));                                        \
      float hn = zs * (HREG) + (1.f - zs) * fmaxf(a, 0.f);                        \
      (HREG) = hn;                                                                \
      __bf16 hb16 = (__bf16)hn;                                                   \
      unsigned pk = ((unsigned)*reinterpret_cast<u16*>(&hb16) << 16) | (tag + 1u);\
      unsigned* pp = hbuf + (size_t)((t + 1) & 1) * BH + ((GG) * 8 + bl) * H_ + col; \
      asm volatile("global_store_dword %0, %1, off sc0 sc1"                       \
                   :: "v"(pp), "v"(pk) : "memory");                               \
      __builtin_nontemporal_store(hn, &out[((size_t)((GG) * 8 + bl) * T_ + t) * H_ + col]); \
    }                                                                             \
  }

#pragma unroll 1
  for (int t = 0; t < T_; ++t) {
    PHASE(0, hreg0, wnx0, wnx1)
    PHASE(1, hreg1, wnx1, wnx0)
  }
#undef PHASE
#undef LOADB
#undef TAGCHK
#undef UNPACK_ROW
#undef ISSUE_W
}

// ---------------- host ----------------
extern "C" void kernel_launch(void* const* d_in, const int* in_sizes, int n_in,
                              void* d_out, int out_size, void* d_ws, size_t ws_size,
                              hipStream_t stream) {
  (void)in_sizes; (void)n_in; (void)out_size; (void)ws_size;
  const float* x = (const float*)d_in[0];
  const float* Ww = (const float*)d_in[1];
  const float* Uw = (const float*)d_in[2];
  const float* gamma = (const float*)d_in[3];
  const float* beta = (const float*)d_in[4];
  const float* h0 = (const float*)d_in[5];
  float* out = (float*)d_out;

  char* p = (char*)d_ws;
  u16* xb = (u16*)p;      p += (size_t)8192 * 512 * 2;   // 8 MB
  u16* Wb = (u16*)p;      p += (size_t)2048 * 512 * 2;   // 2 MB
  u16* Ub = (u16*)p;      p += (size_t)2048 * 1024 * 2;  // 4 MB
  float* w = (float*)p;   p += (size_t)8192 * 2048 * 4;  // 64 MB  [T][B][G]
  unsigned* hbuf = (unsigned*)p; p += (size_t)2 * BH * 4; // 128 KB tagged dwords
  unsigned* elect = (unsigned*)p; p += 64;                // election state

  // tag 0 != any real tag; election counters + winner zeroed (contiguous)
  hipMemsetAsync(hbuf, 0, (size_t)2 * BH * 4 + 64, stream);
  cast_f32_bf16<<<512, 256, 0, stream>>>(x, xb, 8192 * 512);
  cast_f32_bf16<<<256, 256, 0, stream>>>(Ww, Wb, 2048 * 512);
  cast_f32_bf16<<<256, 256, 0, stream>>>(Uw, Ub, 2048 * 1024);
  gemm_xW<<<512, 256, 0, stream>>>(xb, Wb, w);
  layernorm_rows<<<8192, 256, 0, stream>>>(w, gamma, beta);

  const float* wc = w;
  const u16* Ubc = Ub;
  void* args[6] = { (void*)&wc, (void*)&Ubc, (void*)&h0, (void*)&out,
                    (void*)&hbuf, (void*)&elect };
  hipLaunchCooperativeKernel((void*)ligru_scan, dim3(256), dim3(512), args, 0, stream);
}

// Round 7
// 4599.061 us; speedup vs baseline: 1.0408x; 1.0408x over previous
//
#include <hip/hip_runtime.h>
#include <hip/hip_cooperative_groups.h>
#include <cmath>

typedef __bf16 bf16x8 __attribute__((ext_vector_type(8)));
typedef float floatx4 __attribute__((ext_vector_type(4)));
typedef unsigned ux4 __attribute__((ext_vector_type(4)));
typedef unsigned short u16;

#define B_ 16
#define T_ 512
#define D_ 512
#define H_ 1024
#define G_ 2048  // 2H
#define BH (B_ * H_)
#define HP 1034  // pitch u16: 2068 B (odd dword count) -> rows spread over bank
                 // groups; 2.2e7 -> ~7e6 conflicts (R5/R6-validated mechanism)

// ---------------- cast fp32 -> bf16 (RNE) ----------------
__global__ void cast_f32_bf16(const float* __restrict__ src, u16* __restrict__ dst, int n) {
  int i = blockIdx.x * blockDim.x + threadIdx.x;
  int stride = gridDim.x * blockDim.x;
  for (; i < n; i += stride) {
    __bf16 b = (__bf16)src[i];
    dst[i] = *reinterpret_cast<u16*>(&b);
  }
}

// ---------------- w = x @ W^T  (bf16 MFMA, fp32 out), layout w[t][b][2H] ----------------
__launch_bounds__(256, 1)
__global__ void gemm_xW(const u16* __restrict__ xb, const u16* __restrict__ Wb,
                        float* __restrict__ w) {
  const int lane = threadIdx.x & 63;
  const int wv = threadIdx.x >> 6;
  const int rt0 = blockIdx.x * 16;
  const int bidx = rt0 >> 9;
  const int t0 = rt0 & 511;
  const int am = lane & 15;
  const int kq = lane >> 4;

  bf16x8 af[16];
  {
    const u16* xrow = xb + (size_t)(rt0 + am) * D_ + kq * 8;
#pragma unroll
    for (int kk = 0; kk < 16; ++kk)
      af[kk] = *reinterpret_cast<const bf16x8*>(xrow + kk * 32);
  }

#pragma unroll 1
  for (int nt = 0; nt < 32; ++nt) {
    const int n0 = wv * 512 + nt * 16;
    floatx4 acc = {0.f, 0.f, 0.f, 0.f};
    const u16* wrow = Wb + (size_t)(n0 + am) * D_ + kq * 8;
#pragma unroll
    for (int kk = 0; kk < 16; ++kk) {
      bf16x8 bfr = *reinterpret_cast<const bf16x8*>(wrow + kk * 32);
      acc = __builtin_amdgcn_mfma_f32_16x16x32_bf16(af[kk], bfr, acc, 0, 0, 0);
    }
#pragma unroll
    for (int i = 0; i < 4; ++i) {
      int m = kq * 4 + i;
      w[(size_t)((t0 + m) * 16 + bidx) * G_ + n0 + am] = acc[i];
    }
  }
}

// ---------------- in-place LayerNorm over rows of 2048 ----------------
__launch_bounds__(256, 1)
__global__ void layernorm_rows(float* __restrict__ w, const float* __restrict__ gamma,
                               const float* __restrict__ beta) {
  float* r = w + (size_t)blockIdx.x * G_;
  float v[8];
  float s = 0.f, ss = 0.f;
#pragma unroll
  for (int i = 0; i < 8; ++i) {
    v[i] = r[threadIdx.x + i * 256];
    s += v[i];
    ss += v[i] * v[i];
  }
#pragma unroll
  for (int d = 1; d < 64; d <<= 1) {
    s += __shfl_xor(s, d, 64);
    ss += __shfl_xor(ss, d, 64);
  }
  __shared__ float ls[4], lss[4];
  const int wv = threadIdx.x >> 6;
  if ((threadIdx.x & 63) == 0) { ls[wv] = s; lss[wv] = ss; }
  __syncthreads();
  float S = ls[0] + ls[1] + ls[2] + ls[3];
  float SS = lss[0] + lss[1] + lss[2] + lss[3];
  float mu = S * (1.f / 2048.f);
  float var = SS * (1.f / 2048.f) - mu * mu;
  float rs = rsqrtf(var + 1e-5f);
#pragma unroll
  for (int i = 0; i < 8; ++i) {
    int g = threadIdx.x + i * 256;
    r[g] = (v[i] - mu) * rs * gamma[g] + beta[g];
  }
}

// ---------------- persistent LiGRU scan: R4 base + early-issue speculation --------
// R4 (passing, 1552us scan): role split (waves 0-3 update/publish, never wait
// vmcnt; waves 4-7 poll/stage, never store) + XCD election + sc0 speculative
// bundles + fence-free sc0 -> sc0sc1 escalating retry. Its floor: spec bundle was
// issued post-barrier-B, ~0.15us before the next phase's vmcnt(0) wait -> the
// whole poll RT exposed every phase.
// R7 changes (only these):
//  (1) EARLY ISSUE: spec bundle issued right after barrier A (pre-MFMA). Flight
//      now covers MFMA + barrier B + update (~0.4-0.5us of the RT hidden).
//      Local publish for that data happened >= 1 phase earlier (program order);
//      cross-block skew is caught by the tag-retry net as always.
//  (2) HP 1032 -> 1034 (odd-dword pitch, R5/R6-validated conflict fix).
__launch_bounds__(512, 1)
__global__ void ligru_scan(const float* __restrict__ w, const u16* __restrict__ Ub,
                           const float* __restrict__ h0, float* __restrict__ out,
                           unsigned* __restrict__ hbuf, unsigned* __restrict__ elect) {
  // ---- election: claim a slot on my XCD; first XCD to 32 slots wins ----
  __shared__ unsigned s_role;
  if (threadIdx.x == 0) {
    unsigned xcc;
    asm volatile("s_getreg_b32 %0, hwreg(HW_REG_XCC_ID)" : "=s"(xcc));
    xcc &= 7u;
    unsigned ticket = atomicAdd(&elect[xcc], 1u);
    if (ticket == 31u) atomicCAS(&elect[8], 0u, xcc + 1u);
    unsigned wn;
    while ((wn = atomicAdd(&elect[8], 0u)) == 0u) __builtin_amdgcn_s_sleep(8);
    s_role = (wn == xcc + 1u && ticket < 32u) ? ticket : 0xFFFFFFFFu;
  }
  __syncthreads();
  const unsigned role = s_role;
  if (role == 0xFFFFFFFFu) return;  // not a worker

  const int tid = threadIdx.x;
  const int lane = tid & 63;
  const int wv = tid >> 6;
  const int am = lane & 15;
  const int kq = lane >> 4;
  const int j0 = (int)role * 32;
  const bool loader = (tid >= 256);
  const int jt = wv & 3;   // tile 0..3
  const int kh = wv >> 2;  // 0 = updater waves, 1 = loader waves

  __shared__ u16 lds_h[16 * HP];         // rows g*8..g*8+7 = group g h (bf16 bits)
  __shared__ float lds_r[4][2][16][16];  // [tile][K-half][m-row][n-col] partials
  __shared__ float lds_w[2][8][2][32];   // [group][batch][gate][col] staged w_t

  const int grow = (am < 8) ? (j0 + 8 * jt + am) : (H_ + j0 + 8 * jt + (am - 8));

  // U fragments: 16 gate-rows x K=512 half, register resident
  bf16x8 uf[16];
  {
    const u16* urow = Ub + (size_t)grow * H_ + kh * 512 + kq * 8;
#pragma unroll
    for (int kk = 0; kk < 16; ++kk)
      uf[kk] = *reinterpret_cast<const bf16x8*>(urow + kk * 32);
  }

  // updater mapping: thread owns (batch bl of each group, col jj)
  const int bl = tid >> 5;   // 0..7 for updaters
  const int jj = tid & 31;
  const int col = j0 + jj;
  float hreg0 = 0.f, hreg1 = 0.f;

  // loader mapping
  const int li = tid & 255;        // 0..255
  const int wb = li >> 5;          // w batch-local
  const int wgt = (li >> 4) & 1;   // w gate
  const int wc2 = (li & 15) * 2;   // w col pair
  ux4 chv0, chv1, chv2, chv3, chv4, chv5, chv6, chv7;
  uint2 wnx;

#define LOADB(SCSTR, cb)                                                          \
  asm volatile("global_load_dwordx4 %0, %8, off " SCSTR "\n\t"                    \
               "global_load_dwordx4 %1, %9, off " SCSTR "\n\t"                    \
               "global_load_dwordx4 %2, %10, off " SCSTR "\n\t"                   \
               "global_load_dwordx4 %3, %11, off " SCSTR "\n\t"                   \
               "global_load_dwordx4 %4, %12, off " SCSTR "\n\t"                   \
               "global_load_dwordx4 %5, %13, off " SCSTR "\n\t"                   \
               "global_load_dwordx4 %6, %14, off " SCSTR "\n\t"                   \
               "global_load_dwordx4 %7, %15, off " SCSTR                          \
               : "=&v"(chv0), "=&v"(chv1), "=&v"(chv2), "=&v"(chv3),              \
                 "=&v"(chv4), "=&v"(chv5), "=&v"(chv6), "=&v"(chv7)               \
               : "v"(cb), "v"((cb) + 1024), "v"((cb) + 2048), "v"((cb) + 3072),   \
                 "v"((cb) + 4096), "v"((cb) + 5120), "v"((cb) + 6144),            \
                 "v"((cb) + 7168)                                                 \
               : "memory")

#define TAGCHK(tg)                                                                \
  ((((chv0.x ^ (tg)) | (chv0.y ^ (tg)) | (chv0.z ^ (tg)) | (chv0.w ^ (tg)) |      \
     (chv1.x ^ (tg)) | (chv1.y ^ (tg)) | (chv1.z ^ (tg)) | (chv1.w ^ (tg)) |      \
     (chv2.x ^ (tg)) | (chv2.y ^ (tg)) | (chv2.z ^ (tg)) | (chv2.w ^ (tg)) |      \
     (chv3.x ^ (tg)) | (chv3.y ^ (tg)) | (chv3.z ^ (tg)) | (chv3.w ^ (tg)) |      \
     (chv4.x ^ (tg)) | (chv4.y ^ (tg)) | (chv4.z ^ (tg)) | (chv4.w ^ (tg)) |      \
     (chv5.x ^ (tg)) | (chv5.y ^ (tg)) | (chv5.z ^ (tg)) | (chv5.w ^ (tg)) |      \
     (chv6.x ^ (tg)) | (chv6.y ^ (tg)) | (chv6.z ^ (tg)) | (chv6.w ^ (tg)) |      \
     (chv7.x ^ (tg)) | (chv7.y ^ (tg)) | (chv7.z ^ (tg)) | (chv7.w ^ (tg))) &     \
    0xFFFFu))

#define UNPACK_ROW(C, GG)                                                         \
  {                                                                               \
    unsigned lo = (chv##C.x >> 16) | (chv##C.y & 0xFFFF0000u);                    \
    unsigned hi = (chv##C.z >> 16) | (chv##C.w & 0xFFFF0000u);                    \
    uint2 pk2; pk2.x = lo; pk2.y = hi;                                            \
    *reinterpret_cast<uint2*>(&lds_h[((GG) * 8 + (C)) * HP + 4 * li]) = pk2;      \
  }

  // ---- init ----
  if (!loader) {
    hreg0 = h0[col];
    hreg1 = hreg0;
    __bf16 hb = (__bf16)hreg0;
    unsigned pk = ((unsigned)*reinterpret_cast<u16*>(&hb) << 16) | 1u;
    unsigned* p0 = hbuf + (0 * 8 + bl) * H_ + col;
    unsigned* p1 = hbuf + (8 + bl) * H_ + col;
    asm volatile("global_store_dword %0, %2, off sc0 sc1\n\t"
                 "global_store_dword %1, %2, off sc0 sc1"
                 :: "v"(p0), "v"(p1), "v"(pk) : "memory");
  } else {
    // W(0, group 0) and B(0, group 0)
    const float* ws = w + (size_t)wb * G_ + wgt * H_ + j0 + wc2;
    asm volatile("global_load_dwordx2 %0, %1, off nt"
                 : "=&v"(wnx) : "v"(ws) : "memory");
    const unsigned* nb = hbuf + 4 * li;
    LOADB("sc0", nb);
  }

#define PHASE(GG, HREG)                                                           \
  {                                                                               \
    const unsigned tag = (unsigned)(t + 1);                                       \
    const int tn = (GG == 0) ? t : ((t + 1 < T_) ? (t + 1) : t);                  \
    const int gn = GG ^ 1;                                                        \
    if (loader) {                                                                 \
      asm volatile("s_waitcnt vmcnt(0)"                                           \
                   : "+v"(chv0), "+v"(chv1), "+v"(chv2), "+v"(chv3),              \
                     "+v"(chv4), "+v"(chv5), "+v"(chv6), "+v"(chv7),              \
                     "+v"(wnx) :: "memory");                                      \
      __builtin_amdgcn_sched_barrier(0);                                          \
      unsigned bad = TAGCHK(tag);                                                 \
      if (bad) {                                                                  \
        const unsigned* cb = hbuf + (size_t)(t & 1) * BH + (GG) * 8192 + 4 * li;  \
        unsigned rounds = 0;                                                      \
        do {                                                                      \
          if (rounds == 0) {                                                      \
            LOADB("sc0", cb);                                                     \
          } else {                                                                \
            LOADB("sc0 sc1", cb);                                                 \
          }                                                                       \
          asm volatile("s_waitcnt vmcnt(0)"                                       \
                       : "+v"(chv0), "+v"(chv1), "+v"(chv2), "+v"(chv3),          \
                         "+v"(chv4), "+v"(chv5), "+v"(chv6), "+v"(chv7)           \
                       :: "memory");                                              \
          bad = TAGCHK(tag);                                                      \
        } while (bad && ++rounds < 4096u);                                        \
      }                                                                           \
      UNPACK_ROW(0, GG) UNPACK_ROW(1, GG) UNPACK_ROW(2, GG) UNPACK_ROW(3, GG)     \
      UNPACK_ROW(4, GG) UNPACK_ROW(5, GG) UNPACK_ROW(6, GG) UNPACK_ROW(7, GG)     \
      *reinterpret_cast<uint2*>(&lds_w[GG][wb][wgt][wc2]) = wnx;                  \
      asm volatile("s_waitcnt lgkmcnt(0)" ::: "memory");                          \
      /* issue w for NEXT phase (full phase of slack before its use) */           \
      {                                                                           \
        const float* ws = w + (size_t)(tn * 16 + gn * 8 + wb) * G_ +              \
                          wgt * H_ + j0 + wc2;                                    \
        asm volatile("global_load_dwordx2 %0, %1, off nt"                         \
                     : "=&v"(wnx) : "v"(ws) : "memory");                          \
      }                                                                           \
    }                                                                             \
    __builtin_amdgcn_s_barrier(); /* (A) staging complete */                      \
    __builtin_amdgcn_sched_barrier(0);                                            \
    if (loader) {                                                                 \
      /* EARLY ISSUE: spec bundle for NEXT phase, pre-MFMA -> RT hides under      \
         MFMA + barrier B + update (data published >= 1 phase ago locally) */     \
      const unsigned* nb = hbuf + (size_t)(tn & 1) * BH + gn * 8192 + 4 * li;     \
      LOADB("sc0", nb);                                                           \
    }                                                                             \
    __builtin_amdgcn_sched_barrier(0);                                            \
    floatx4 acc0 = {0, 0, 0, 0}, acc1 = {0, 0, 0, 0};                             \
    {                                                                             \
      const u16* hb = &lds_h[am * HP + kh * 512 + kq * 8];                        \
      _Pragma("unroll")                                                           \
      for (int kk = 0; kk < 8; ++kk) {                                            \
        bf16x8 x0 = *reinterpret_cast<const bf16x8*>(hb + (kk + 0) * 32);         \
        bf16x8 x1 = *reinterpret_cast<const bf16x8*>(hb + (kk + 8) * 32);         \
        acc0 = __builtin_amdgcn_mfma_f32_16x16x32_bf16(x0, uf[kk + 0], acc0, 0, 0, 0); \
        acc1 = __builtin_amdgcn_mfma_f32_16x16x32_bf16(x1, uf[kk + 8], acc1, 0, 0, 0); \
      }                                                                           \
    }                                                                             \
    floatx4 acc = acc0 + acc1;                                                    \
    _Pragma("unroll")                                                             \
    for (int i = 0; i < 4; ++i)                                                   \
      lds_r[jt][kh][kq * 4 + i][am] = acc[i];                                     \
    asm volatile("s_waitcnt lgkmcnt(0)" ::: "memory");                            \
    __builtin_amdgcn_s_barrier(); /* (B) partials complete */                     \
    __builtin_amdgcn_sched_barrier(0);                                            \
    if (!loader) {                                                                \
      const int tl = jj >> 3, cc = jj & 7;                                        \
      const int mr = (GG) * 8 + bl;                                               \
      float a = lds_r[tl][0][mr][cc] + lds_r[tl][1][mr][cc] +                     \
                lds_w[GG][bl][0][jj];                                             \
      float z = lds_r[tl][0][mr][8 + cc] + lds_r[tl][1][mr][8 + cc] +             \
                lds_w[GG][bl][1][jj];                                             \
      float zs = 1.f / (1.f + __expf(-z));                                        \
      float hn = zs * (HREG) + (1.f - zs) * fmaxf(a, 0.f);                        \
      (HREG) = hn;                                                                \
      __bf16 hb16 = (__bf16)hn;                                                   \
      unsigned pk = ((unsigned)*reinterpret_cast<u16*>(&hb16) << 16) | (tag + 1u);\
      unsigned* pp = hbuf + (size_t)((t + 1) & 1) * BH + ((GG) * 8 + bl) * H_ + col; \
      asm volatile("global_store_dword %0, %1, off sc0 sc1"                       \
                   :: "v"(pp), "v"(pk) : "memory");                               \
      __builtin_nontemporal_store(hn, &out[((size_t)((GG) * 8 + bl) * T_ + t) * H_ + col]); \
    }                                                                             \
  }

#pragma unroll 1
  for (int t = 0; t < T_; ++t) {
    PHASE(0, hreg0)
    PHASE(1, hreg1)
  }
#undef PHASE
#undef LOADB
#undef TAGCHK
#undef UNPACK_ROW
}

// ---------------- host ----------------
extern "C" void kernel_launch(void* const* d_in, const int* in_sizes, int n_in,
                              void* d_out, int out_size, void* d_ws, size_t ws_size,
                              hipStream_t stream) {
  (void)in_sizes; (void)n_in; (void)out_size; (void)ws_size;
  const float* x = (const float*)d_in[0];
  const float* Ww = (const float*)d_in[1];
  const float* Uw = (const float*)d_in[2];
  const float* gamma = (const float*)d_in[3];
  const float* beta = (const float*)d_in[4];
  const float* h0 = (const float*)d_in[5];
  float* out = (float*)d_out;

  char* p = (char*)d_ws;
  u16* xb = (u16*)p;      p += (size_t)8192 * 512 * 2;   // 8 MB
  u16* Wb = (u16*)p;      p += (size_t)2048 * 512 * 2;   // 2 MB
  u16* Ub = (u16*)p;      p += (size_t)2048 * 1024 * 2;  // 4 MB
  float* w = (float*)p;   p += (size_t)8192 * 2048 * 4;  // 64 MB  [T][B][G]
  unsigned* hbuf = (unsigned*)p; p += (size_t)2 * BH * 4; // 128 KB tagged dwords
  unsigned* elect = (unsigned*)p; p += 64;                // election state

  // tag 0 != any real tag; election counters + winner zeroed (contiguous)
  hipMemsetAsync(hbuf, 0, (size_t)2 * BH * 4 + 64, stream);
  cast_f32_bf16<<<512, 256, 0, stream>>>(x, xb, 8192 * 512);
  cast_f32_bf16<<<256, 256, 0, stream>>>(Ww, Wb, 2048 * 512);
  cast_f32_bf16<<<256, 256, 0, stream>>>(Uw, Ub, 2048 * 1024);
  gemm_xW<<<512, 256, 0, stream>>>(xb, Wb, w);
  layernorm_rows<<<8192, 256, 0, stream>>>(w, gamma, beta);

  const float* wc = w;
  const u16* Ubc = Ub;
  void* args[6] = { (void*)&wc, (void*)&Ubc, (void*)&h0, (void*)&out,
                    (void*)&hbuf, (void*)&elect };
  hipLaunchCooperativeKernel((void*)ligru_scan, dim3(256), dim3(512), args, 0, stream);
}

// Round 8
// 1698.700 us; speedup vs baseline: 2.8179x; 2.7074x over previous
//
#include <hip/hip_runtime.h>
#include <hip/hip_cooperative_groups.h>
#include <cmath>

typedef __bf16 bf16x8 __attribute__((ext_vector_type(8)));
typedef float floatx4 __attribute__((ext_vector_type(4)));
typedef unsigned ux4 __attribute__((ext_vector_type(4)));
typedef unsigned short u16;

#define B_ 16
#define T_ 512
#define D_ 512
#define H_ 1024
#define G_ 2048  // 2H
#define BH (B_ * H_)
#define HP 1032  // pitch u16 = 2064 B = 129*16B. MUST stay a multiple of 8 u16:
                 // non-16B-multiple pitches (R5:1058, R6/R7:1034) misalign the
                 // ds_read_b128 A-fragment reads on odd rows -> HW splits them
                 // -> 3x phase regression (the R5/R6/R7 confound).

// ---------------- cast fp32 -> bf16 (RNE) ----------------
__global__ void cast_f32_bf16(const float* __restrict__ src, u16* __restrict__ dst, int n) {
  int i = blockIdx.x * blockDim.x + threadIdx.x;
  int stride = gridDim.x * blockDim.x;
  for (; i < n; i += stride) {
    __bf16 b = (__bf16)src[i];
    dst[i] = *reinterpret_cast<u16*>(&b);
  }
}

// ---------------- w = x @ W^T  (bf16 MFMA, fp32 out), layout w[t][b][2H] ----------------
__launch_bounds__(256, 1)
__global__ void gemm_xW(const u16* __restrict__ xb, const u16* __restrict__ Wb,
                        float* __restrict__ w) {
  const int lane = threadIdx.x & 63;
  const int wv = threadIdx.x >> 6;
  const int rt0 = blockIdx.x * 16;
  const int bidx = rt0 >> 9;
  const int t0 = rt0 & 511;
  const int am = lane & 15;
  const int kq = lane >> 4;

  bf16x8 af[16];
  {
    const u16* xrow = xb + (size_t)(rt0 + am) * D_ + kq * 8;
#pragma unroll
    for (int kk = 0; kk < 16; ++kk)
      af[kk] = *reinterpret_cast<const bf16x8*>(xrow + kk * 32);
  }

#pragma unroll 1
  for (int nt = 0; nt < 32; ++nt) {
    const int n0 = wv * 512 + nt * 16;
    floatx4 acc = {0.f, 0.f, 0.f, 0.f};
    const u16* wrow = Wb + (size_t)(n0 + am) * D_ + kq * 8;
#pragma unroll
    for (int kk = 0; kk < 16; ++kk) {
      bf16x8 bfr = *reinterpret_cast<const bf16x8*>(wrow + kk * 32);
      acc = __builtin_amdgcn_mfma_f32_16x16x32_bf16(af[kk], bfr, acc, 0, 0, 0);
    }
#pragma unroll
    for (int i = 0; i < 4; ++i) {
      int m = kq * 4 + i;
      w[(size_t)((t0 + m) * 16 + bidx) * G_ + n0 + am] = acc[i];
    }
  }
}

// ---------------- in-place LayerNorm over rows of 2048 ----------------
__launch_bounds__(256, 1)
__global__ void layernorm_rows(float* __restrict__ w, const float* __restrict__ gamma,
                               const float* __restrict__ beta) {
  float* r = w + (size_t)blockIdx.x * G_;
  float v[8];
  float s = 0.f, ss = 0.f;
#pragma unroll
  for (int i = 0; i < 8; ++i) {
    v[i] = r[threadIdx.x + i * 256];
    s += v[i];
    ss += v[i] * v[i];
  }
#pragma unroll
  for (int d = 1; d < 64; d <<= 1) {
    s += __shfl_xor(s, d, 64);
    ss += __shfl_xor(ss, d, 64);
  }
  __shared__ float ls[4], lss[4];
  const int wv = threadIdx.x >> 6;
  if ((threadIdx.x & 63) == 0) { ls[wv] = s; lss[wv] = ss; }
  __syncthreads();
  float S = ls[0] + ls[1] + ls[2] + ls[3];
  float SS = lss[0] + lss[1] + lss[2] + lss[3];
  float mu = S * (1.f / 2048.f);
  float var = SS * (1.f / 2048.f) - mu * mu;
  float rs = rsqrtf(var + 1e-5f);
#pragma unroll
  for (int i = 0; i < 8; ++i) {
    int g = threadIdx.x + i * 256;
    r[g] = (v[i] - mu) * rs * gamma[g] + beta[g];
  }
}

// ---------------- persistent LiGRU scan: R4 protocol, de-poisoned pipeline --------
// Protocol (R4-validated, 1552us): role split (waves 0-3 update/publish sc0sc1,
// never wait vmcnt; waves 4-7 poll/stage, never store) + XCD election + sc0
// speculative bundles + fence-free sc0 -> sc0sc1 escalating retry.
// R8 deltas vs R4 (each previously run, confounded only by the HP poison):
//  (1) HP stays 1032 (16B-multiple pitch; see #define comment).
//  (2) w nt-loads: ping-pong regs, issued at phase START one phase ahead,
//      retired by counted vmcnt(1) -> full phase of flight for the ~0.9us HBM
//      latency (R6 mechanism).
//  (3) spec bundle issued post-barrier-A (pre-MFMA): RT hides under
//      MFMA + barrier B + update (R7 mechanism).
__launch_bounds__(512, 1)
__global__ void ligru_scan(const float* __restrict__ w, const u16* __restrict__ Ub,
                           const float* __restrict__ h0, float* __restrict__ out,
                           unsigned* __restrict__ hbuf, unsigned* __restrict__ elect) {
  // ---- election: claim a slot on my XCD; first XCD to 32 slots wins ----
  __shared__ unsigned s_role;
  if (threadIdx.x == 0) {
    unsigned xcc;
    asm volatile("s_getreg_b32 %0, hwreg(HW_REG_XCC_ID)" : "=s"(xcc));
    xcc &= 7u;
    unsigned ticket = atomicAdd(&elect[xcc], 1u);
    if (ticket == 31u) atomicCAS(&elect[8], 0u, xcc + 1u);
    unsigned wn;
    while ((wn = atomicAdd(&elect[8], 0u)) == 0u) __builtin_amdgcn_s_sleep(8);
    s_role = (wn == xcc + 1u && ticket < 32u) ? ticket : 0xFFFFFFFFu;
  }
  __syncthreads();
  const unsigned role = s_role;
  if (role == 0xFFFFFFFFu) return;  // not a worker

  const int tid = threadIdx.x;
  const int lane = tid & 63;
  const int wv = tid >> 6;
  const int am = lane & 15;
  const int kq = lane >> 4;
  const int j0 = (int)role * 32;
  const bool loader = (tid >= 256);
  const int jt = wv & 3;   // tile 0..3
  const int kh = wv >> 2;  // 0 = updater waves, 1 = loader waves

  __shared__ u16 lds_h[16 * HP];         // rows g*8..g*8+7 = group g h (bf16 bits)
  __shared__ float lds_r[4][2][16][16];  // [tile][K-half][m-row][n-col] partials
  __shared__ float lds_w[2][8][2][32];   // [group][batch][gate][col] staged w_t

  const int grow = (am < 8) ? (j0 + 8 * jt + am) : (H_ + j0 + 8 * jt + (am - 8));

  // U fragments: 16 gate-rows x K=512 half, register resident
  bf16x8 uf[16];
  {
    const u16* urow = Ub + (size_t)grow * H_ + kh * 512 + kq * 8;
#pragma unroll
    for (int kk = 0; kk < 16; ++kk)
      uf[kk] = *reinterpret_cast<const bf16x8*>(urow + kk * 32);
  }

  // updater mapping: thread owns (batch bl of each group, col jj)
  const int bl = tid >> 5;   // 0..7 for updaters
  const int jj = tid & 31;
  const int col = j0 + jj;
  float hreg0 = 0.f, hreg1 = 0.f;

  // loader mapping
  const int li = tid & 255;        // 0..255
  const int wb = li >> 5;          // w batch-local
  const int wgt = (li >> 4) & 1;   // w gate
  const int wc2 = (li & 15) * 2;   // w col pair
  ux4 chv0, chv1, chv2, chv3, chv4, chv5, chv6, chv7;
  uint2 wnxA, wnxB;                // w ping-pong (A = even phases/G0, B = odd/G1)

#define LOADB(SCSTR, cb)                                                          \
  asm volatile("global_load_dwordx4 %0, %8, off " SCSTR "\n\t"                    \
               "global_load_dwordx4 %1, %9, off " SCSTR "\n\t"                    \
               "global_load_dwordx4 %2, %10, off " SCSTR "\n\t"                   \
               "global_load_dwordx4 %3, %11, off " SCSTR "\n\t"                   \
               "global_load_dwordx4 %4, %12, off " SCSTR "\n\t"                   \
               "global_load_dwordx4 %5, %13, off " SCSTR "\n\t"                   \
               "global_load_dwordx4 %6, %14, off " SCSTR "\n\t"                   \
               "global_load_dwordx4 %7, %15, off " SCSTR                          \
               : "=&v"(chv0), "=&v"(chv1), "=&v"(chv2), "=&v"(chv3),              \
                 "=&v"(chv4), "=&v"(chv5), "=&v"(chv6), "=&v"(chv7)               \
               : "v"(cb), "v"((cb) + 1024), "v"((cb) + 2048), "v"((cb) + 3072),   \
                 "v"((cb) + 4096), "v"((cb) + 5120), "v"((cb) + 6144),            \
                 "v"((cb) + 7168)                                                 \
               : "memory")

#define TAGCHK(tg)                                                                \
  ((((chv0.x ^ (tg)) | (chv0.y ^ (tg)) | (chv0.z ^ (tg)) | (chv0.w ^ (tg)) |      \
     (chv1.x ^ (tg)) | (chv1.y ^ (tg)) | (chv1.z ^ (tg)) | (chv1.w ^ (tg)) |      \
     (chv2.x ^ (tg)) | (chv2.y ^ (tg)) | (chv2.z ^ (tg)) | (chv2.w ^ (tg)) |      \
     (chv3.x ^ (tg)) | (chv3.y ^ (tg)) | (chv3.z ^ (tg)) | (chv3.w ^ (tg)) |      \
     (chv4.x ^ (tg)) | (chv4.y ^ (tg)) | (chv4.z ^ (tg)) | (chv4.w ^ (tg)) |      \
     (chv5.x ^ (tg)) | (chv5.y ^ (tg)) | (chv5.z ^ (tg)) | (chv5.w ^ (tg)) |      \
     (chv6.x ^ (tg)) | (chv6.y ^ (tg)) | (chv6.z ^ (tg)) | (chv6.w ^ (tg)) |      \
     (chv7.x ^ (tg)) | (chv7.y ^ (tg)) | (chv7.z ^ (tg)) | (chv7.w ^ (tg))) &     \
    0xFFFFu))

#define UNPACK_ROW(C, GG)                                                         \
  {                                                                               \
    unsigned lo = (chv##C.x >> 16) | (chv##C.y & 0xFFFF0000u);                    \
    unsigned hi = (chv##C.z >> 16) | (chv##C.w & 0xFFFF0000u);                    \
    uint2 pk2; pk2.x = lo; pk2.y = hi;                                            \
    *reinterpret_cast<uint2*>(&lds_h[((GG) * 8 + (C)) * HP + 4 * li]) = pk2;      \
  }

#define ISSUE_W(DST, trow)                                                        \
  {                                                                               \
    const float* ws_ = w + (size_t)(trow) * G_ + wgt * H_ + j0 + wc2;             \
    asm volatile("global_load_dwordx2 %0, %1, off nt"                             \
                 : "=&v"(DST) : "v"(ws_) : "memory");                             \
  }

  // ---- init ----
  if (!loader) {
    hreg0 = h0[col];
    hreg1 = hreg0;
    __bf16 hb = (__bf16)hreg0;
    unsigned pk = ((unsigned)*reinterpret_cast<u16*>(&hb) << 16) | 1u;
    unsigned* p0 = hbuf + (0 * 8 + bl) * H_ + col;
    unsigned* p1 = hbuf + (8 + bl) * H_ + col;
    asm volatile("global_store_dword %0, %2, off sc0 sc1\n\t"
                 "global_store_dword %1, %2, off sc0 sc1"
                 :: "v"(p0), "v"(p1), "v"(pk) : "memory");
  } else {
    // issue order matters for counted vmcnt: w(phase0) oldest, then bundle(phase0)
    ISSUE_W(wnxA, 0 * 16 + 0 * 8 + wb);   // w for (t=0, G=0)
    const unsigned* nb = hbuf + 4 * li;   // bundle (t=0, G=0)
    LOADB("sc0", nb);
  }

#define PHASE(GG, HREG, WCUR, WNXT)                                               \
  {                                                                               \
    const unsigned tag = (unsigned)(t + 1);                                       \
    const int tn = (GG == 0) ? t : ((t + 1 < T_) ? (t + 1) : t);                  \
    const int gn = GG ^ 1;                                                        \
    if (loader) {                                                                 \
      /* issue NEXT phase's w first: full phase of flight before its drain */     \
      ISSUE_W(WNXT, tn * 16 + gn * 8 + wb);                                       \
      /* counted wait: drains w_cur + bundle_cur (9 oldest), leaves w_next */     \
      asm volatile("s_waitcnt vmcnt(1)"                                           \
                   : "+v"(chv0), "+v"(chv1), "+v"(chv2), "+v"(chv3),              \
                     "+v"(chv4), "+v"(chv5), "+v"(chv6), "+v"(chv7),              \
                     "+v"(WCUR) :: "memory");                                     \
      __builtin_amdgcn_sched_barrier(0);                                          \
      unsigned bad = TAGCHK(tag);                                                 \
      if (bad) {                                                                  \
        const unsigned* cb = hbuf + (size_t)(t & 1) * BH + (GG) * 8192 + 4 * li;  \
        unsigned rounds = 0;                                                      \
        do {                                                                      \
          if (rounds == 0) {                                                      \
            LOADB("sc0", cb);                                                     \
          } else {                                                                \
            LOADB("sc0 sc1", cb);                                                 \
          }                                                                       \
          asm volatile("s_waitcnt vmcnt(0)"                                       \
                       : "+v"(chv0), "+v"(chv1), "+v"(chv2), "+v"(chv3),          \
                         "+v"(chv4), "+v"(chv5), "+v"(chv6), "+v"(chv7)           \
                       :: "memory");                                              \
          bad = TAGCHK(tag);                                                      \
        } while (bad && ++rounds < 4096u);                                        \
      }                                                                           \
      UNPACK_ROW(0, GG) UNPACK_ROW(1, GG) UNPACK_ROW(2, GG) UNPACK_ROW(3, GG)     \
      UNPACK_ROW(4, GG) UNPACK_ROW(5, GG) UNPACK_ROW(6, GG) UNPACK_ROW(7, GG)     \
      *reinterpret_cast<uint2*>(&lds_w[GG][wb][wgt][wc2]) = WCUR;                 \
      asm volatile("s_waitcnt lgkmcnt(0)" ::: "memory");                          \
    }                                                                             \
    __builtin_amdgcn_s_barrier(); /* (A) staging complete */                      \
    __builtin_amdgcn_sched_barrier(0);                                            \
    if (loader) {                                                                 \
      /* EARLY ISSUE: spec bundle for NEXT phase, pre-MFMA -> RT hides under      \
         MFMA + barrier B + update (data published >= 1 phase ago) */             \
      const unsigned* nb = hbuf + (size_t)(tn & 1) * BH + gn * 8192 + 4 * li;     \
      LOADB("sc0", nb);                                                           \
    }                                                                             \
    __builtin_amdgcn_sched_barrier(0);                                            \
    floatx4 acc0 = {0, 0, 0, 0}, acc1 = {0, 0, 0, 0};                             \
    {                                                                             \
      const u16* hb = &lds_h[am * HP + kh * 512 + kq * 8];                        \
      _Pragma("unroll")                                                           \
      for (int kk = 0; kk < 8; ++kk) {                                            \
        bf16x8 x0 = *reinterpret_cast<const bf16x8*>(hb + (kk + 0) * 32);         \
        bf16x8 x1 = *reinterpret_cast<const bf16x8*>(hb + (kk + 8) * 32);         \
        acc0 = __builtin_amdgcn_mfma_f32_16x16x32_bf16(x0, uf[kk + 0], acc0, 0, 0, 0); \
        acc1 = __builtin_amdgcn_mfma_f32_16x16x32_bf16(x1, uf[kk + 8], acc1, 0, 0, 0); \
      }                                                                           \
    }                                                                             \
    floatx4 acc = acc0 + acc1;                                                    \
    _Pragma("unroll")                                                             \
    for (int i = 0; i < 4; ++i)                                                   \
      lds_r[jt][kh][kq * 4 + i][am] = acc[i];                                     \
    asm volatile("s_waitcnt lgkmcnt(0)" ::: "memory");                            \
    __builtin_amdgcn_s_barrier(); /* (B) partials complete */                     \
    __builtin_amdgcn_sched_barrier(0);                                            \
    if (!loader) {                                                                \
      const int tl = jj >> 3, cc = jj & 7;                                        \
      const int mr = (GG) * 8 + bl;                                               \
      float a = lds_r[tl][0][mr][cc] + lds_r[tl][1][mr][cc] +                     \
                lds_w[GG][bl][0][jj];                                             \
      float z = lds_r[tl][0][mr][8 + cc] + lds_r[tl][1][mr][8 + cc] +             \
                lds_w[GG][bl][1][jj];                                             \
      float zs = 1.f / (1.f + __expf(-z));                                        \
      float hn = zs * (HREG) + (1.f - zs) * fmaxf(a, 0.f);                        \
      (HREG) = hn;                                                                \
      __bf16 hb16 = (__bf16)hn;                                                   \
      unsigned pk = ((unsigned)*reinterpret_cast<u16*>(&hb16) << 16) | (tag + 1u);\
      unsigned* pp = hbuf + (size_t)((t + 1) & 1) * BH + ((GG) * 8 + bl) * H_ + col; \
      asm volatile("global_store_dword %0, %1, off sc0 sc1"                       \
                   :: "v"(pp), "v"(pk) : "memory");                               \
      __builtin_nontemporal_store(hn, &out[((size_t)((GG) * 8 + bl) * T_ + t) * H_ + col]); \
    }                                                                             \
  }

#pragma unroll 1
  for (int t = 0; t < T_; ++t) {
    PHASE(0, hreg0, wnxA, wnxB)
    PHASE(1, hreg1, wnxB, wnxA)
  }
#undef PHASE
#undef LOADB
#undef TAGCHK
#undef UNPACK_ROW
#undef ISSUE_W
}

// ---------------- host ----------------
extern "C" void kernel_launch(void* const* d_in, const int* in_sizes, int n_in,
                              void* d_out, int out_size, void* d_ws, size_t ws_size,
                              hipStream_t stream) {
  (void)in_sizes; (void)n_in; (void)out_size; (void)ws_size;
  const float* x = (const float*)d_in[0];
  const float* Ww = (const float*)d_in[1];
  const float* Uw = (const float*)d_in[2];
  const float* gamma = (const float*)d_in[3];
  const float* beta = (const float*)d_in[4];
  const float* h0 = (const float*)d_in[5];
  float* out = (float*)d_out;

  char* p = (char*)d_ws;
  u16* xb = (u16*)p;      p += (size_t)8192 * 512 * 2;   // 8 MB
  u16* Wb = (u16*)p;      p += (size_t)2048 * 512 * 2;   // 2 MB
  u16* Ub = (u16*)p;      p += (size_t)2048 * 1024 * 2;  // 4 MB
  float* w = (float*)p;   p += (size_t)8192 * 2048 * 4;  // 64 MB  [T][B][G]
  unsigned* hbuf = (unsigned*)p; p += (size_t)2 * BH * 4; // 128 KB tagged dwords
  unsigned* elect = (unsigned*)p; p += 64;                // election state

  // tag 0 != any real tag; election counters + winner zeroed (contiguous)
  hipMemsetAsync(hbuf, 0, (size_t)2 * BH * 4 + 64, stream);
  cast_f32_bf16<<<512, 256, 0, stream>>>(x, xb, 8192 * 512);
  cast_f32_bf16<<<256, 256, 0, stream>>>(Ww, Wb, 2048 * 512);
  cast_f32_bf16<<<256, 256, 0, stream>>>(Uw, Ub, 2048 * 1024);
  gemm_xW<<<512, 256, 0, stream>>>(xb, Wb, w);
  layernorm_rows<<<8192, 256, 0, stream>>>(w, gamma, beta);

  const float* wc = w;
  const u16* Ubc = Ub;
  void* args[6] = { (void*)&wc, (void*)&Ubc, (void*)&h0, (void*)&out,
                    (void*)&hbuf, (void*)&elect };
  hipLaunchCooperativeKernel((void*)ligru_scan, dim3(256), dim3(512), args, 0, stream);
}

// Round 9
// 1688.817 us; speedup vs baseline: 2.8344x; 1.0059x over previous
//
#include <hip/hip_runtime.h>
#include <hip/hip_cooperative_groups.h>
#include <cmath>

typedef __bf16 bf16x8 __attribute__((ext_vector_type(8)));
typedef float floatx4 __attribute__((ext_vector_type(4)));
typedef unsigned ux4 __attribute__((ext_vector_type(4)));
typedef unsigned short u16;

#define B_ 16
#define T_ 512
#define D_ 512
#define H_ 1024
#define G_ 2048  // 2H
#define BH (B_ * H_)
#define HP 1032  // pitch u16 = 2064 B = 129*16B. MUST stay a multiple of 8 u16:
                 // non-16B-multiple pitches misalign ds_read_b128 on odd rows ->
                 // HW splits them -> 3x regression (R5/R6/R7 confound).

// ---------------- cast fp32 -> bf16 (RNE) ----------------
__global__ void cast_f32_bf16(const float* __restrict__ src, u16* __restrict__ dst, int n) {
  int i = blockIdx.x * blockDim.x + threadIdx.x;
  int stride = gridDim.x * blockDim.x;
  for (; i < n; i += stride) {
    __bf16 b = (__bf16)src[i];
    dst[i] = *reinterpret_cast<u16*>(&b);
  }
}

// ---------------- w = x @ W^T  (bf16 MFMA, fp32 out), layout w[t][b][2H] ----------------
__launch_bounds__(256, 1)
__global__ void gemm_xW(const u16* __restrict__ xb, const u16* __restrict__ Wb,
                        float* __restrict__ w) {
  const int lane = threadIdx.x & 63;
  const int wv = threadIdx.x >> 6;
  const int rt0 = blockIdx.x * 16;
  const int bidx = rt0 >> 9;
  const int t0 = rt0 & 511;
  const int am = lane & 15;
  const int kq = lane >> 4;

  bf16x8 af[16];
  {
    const u16* xrow = xb + (size_t)(rt0 + am) * D_ + kq * 8;
#pragma unroll
    for (int kk = 0; kk < 16; ++kk)
      af[kk] = *reinterpret_cast<const bf16x8*>(xrow + kk * 32);
  }

#pragma unroll 1
  for (int nt = 0; nt < 32; ++nt) {
    const int n0 = wv * 512 + nt * 16;
    floatx4 acc = {0.f, 0.f, 0.f, 0.f};
    const u16* wrow = Wb + (size_t)(n0 + am) * D_ + kq * 8;
#pragma unroll
    for (int kk = 0; kk < 16; ++kk) {
      bf16x8 bfr = *reinterpret_cast<const bf16x8*>(wrow + kk * 32);
      acc = __builtin_amdgcn_mfma_f32_16x16x32_bf16(af[kk], bfr, acc, 0, 0, 0);
    }
#pragma unroll
    for (int i = 0; i < 4; ++i) {
      int m = kq * 4 + i;
      w[(size_t)((t0 + m) * 16 + bidx) * G_ + n0 + am] = acc[i];
    }
  }
}

// ---------------- in-place LayerNorm over rows of 2048 ----------------
__launch_bounds__(256, 1)
__global__ void layernorm_rows(float* __restrict__ w, const float* __restrict__ gamma,
                               const float* __restrict__ beta) {
  float* r = w + (size_t)blockIdx.x * G_;
  float v[8];
  float s = 0.f, ss = 0.f;
#pragma unroll
  for (int i = 0; i < 8; ++i) {
    v[i] = r[threadIdx.x + i * 256];
    s += v[i];
    ss += v[i] * v[i];
  }
#pragma unroll
  for (int d = 1; d < 64; d <<= 1) {
    s += __shfl_xor(s, d, 64);
    ss += __shfl_xor(ss, d, 64);
  }
  __shared__ float ls[4], lss[4];
  const int wv = threadIdx.x >> 6;
  if ((threadIdx.x & 63) == 0) { ls[wv] = s; lss[wv] = ss; }
  __syncthreads();
  float S = ls[0] + ls[1] + ls[2] + ls[3];
  float SS = lss[0] + lss[1] + lss[2] + lss[3];
  float mu = S * (1.f / 2048.f);
  float var = SS * (1.f / 2048.f) - mu * mu;
  float rs = rsqrtf(var + 1e-5f);
#pragma unroll
  for (int i = 0; i < 8; ++i) {
    int g = threadIdx.x + i * 256;
    r[g] = (v[i] - mu) * rs * gamma[g] + beta[g];
  }
}

// ---------------- persistent LiGRU scan: R8 + LDS-path fixes ----------------------
// R8 (passing, best: scan 1491us): role split + XCD election + sc0 spec bundles +
// escalating retry + early bundle issue + counted vmcnt(1) w-prefetch.
// R9 deltas (LDS path only; exchange/protocol byte-identical):
//  (1) A-read BROADCAST DEDUP: MFMA A-fragment reads row GG*8+(am&7) instead of
//      am. Lanes am/am+8 read the SAME address -> LDS broadcast (free) -> A-read
//      data movement halves. Equivalent output: D row m = gates of batch (m&7)
//      of group GG; update reads row GG*8+bl whose batch is bl (unchanged).
//  (2) lds_r padded [4][2][17][17]: removes the structural 4-way bank conflict on
//      partial writes (old addr ≡ i*16+am mod 32, kq vanished; now ≤2-way).
__launch_bounds__(512, 1)
__global__ void ligru_scan(const float* __restrict__ w, const u16* __restrict__ Ub,
                           const float* __restrict__ h0, float* __restrict__ out,
                           unsigned* __restrict__ hbuf, unsigned* __restrict__ elect) {
  // ---- election: claim a slot on my XCD; first XCD to 32 slots wins ----
  __shared__ unsigned s_role;
  if (threadIdx.x == 0) {
    unsigned xcc;
    asm volatile("s_getreg_b32 %0, hwreg(HW_REG_XCC_ID)" : "=s"(xcc));
    xcc &= 7u;
    unsigned ticket = atomicAdd(&elect[xcc], 1u);
    if (ticket == 31u) atomicCAS(&elect[8], 0u, xcc + 1u);
    unsigned wn;
    while ((wn = atomicAdd(&elect[8], 0u)) == 0u) __builtin_amdgcn_s_sleep(8);
    s_role = (wn == xcc + 1u && ticket < 32u) ? ticket : 0xFFFFFFFFu;
  }
  __syncthreads();
  const unsigned role = s_role;
  if (role == 0xFFFFFFFFu) return;  // not a worker

  const int tid = threadIdx.x;
  const int lane = tid & 63;
  const int wv = tid >> 6;
  const int am = lane & 15;
  const int kq = lane >> 4;
  const int j0 = (int)role * 32;
  const bool loader = (tid >= 256);
  const int jt = wv & 3;   // tile 0..3
  const int kh = wv >> 2;  // 0 = updater waves, 1 = loader waves

  __shared__ u16 lds_h[16 * HP];          // rows g*8..g*8+7 = group g h (bf16 bits)
  __shared__ float lds_r[4][2][17][17];   // [tile][K-half][m-row][n-col] padded
  __shared__ float lds_w[2][8][2][32];    // [group][batch][gate][col] staged w_t

  const int grow = (am < 8) ? (j0 + 8 * jt + am) : (H_ + j0 + 8 * jt + (am - 8));

  // U fragments: 16 gate-rows x K=512 half, register resident
  bf16x8 uf[16];
  {
    const u16* urow = Ub + (size_t)grow * H_ + kh * 512 + kq * 8;
#pragma unroll
    for (int kk = 0; kk < 16; ++kk)
      uf[kk] = *reinterpret_cast<const bf16x8*>(urow + kk * 32);
  }

  // updater mapping: thread owns (batch bl of each group, col jj)
  const int bl = tid >> 5;   // 0..7 for updaters
  const int jj = tid & 31;
  const int col = j0 + jj;
  float hreg0 = 0.f, hreg1 = 0.f;

  // loader mapping
  const int li = tid & 255;        // 0..255
  const int wb = li >> 5;          // w batch-local
  const int wgt = (li >> 4) & 1;   // w gate
  const int wc2 = (li & 15) * 2;   // w col pair
  ux4 chv0, chv1, chv2, chv3, chv4, chv5, chv6, chv7;
  uint2 wnxA, wnxB;                // w ping-pong (A = G0 phases, B = G1)

#define LOADB(SCSTR, cb)                                                          \
  asm volatile("global_load_dwordx4 %0, %8, off " SCSTR "\n\t"                    \
               "global_load_dwordx4 %1, %9, off " SCSTR "\n\t"                    \
               "global_load_dwordx4 %2, %10, off " SCSTR "\n\t"                   \
               "global_load_dwordx4 %3, %11, off " SCSTR "\n\t"                   \
               "global_load_dwordx4 %4, %12, off " SCSTR "\n\t"                   \
               "global_load_dwordx4 %5, %13, off " SCSTR "\n\t"                   \
               "global_load_dwordx4 %6, %14, off " SCSTR "\n\t"                   \
               "global_load_dwordx4 %7, %15, off " SCSTR                          \
               : "=&v"(chv0), "=&v"(chv1), "=&v"(chv2), "=&v"(chv3),              \
                 "=&v"(chv4), "=&v"(chv5), "=&v"(chv6), "=&v"(chv7)               \
               : "v"(cb), "v"((cb) + 1024), "v"((cb) + 2048), "v"((cb) + 3072),   \
                 "v"((cb) + 4096), "v"((cb) + 5120), "v"((cb) + 6144),            \
                 "v"((cb) + 7168)                                                 \
               : "memory")

#define TAGCHK(tg)                                                                \
  ((((chv0.x ^ (tg)) | (chv0.y ^ (tg)) | (chv0.z ^ (tg)) | (chv0.w ^ (tg)) |      \
     (chv1.x ^ (tg)) | (chv1.y ^ (tg)) | (chv1.z ^ (tg)) | (chv1.w ^ (tg)) |      \
     (chv2.x ^ (tg)) | (chv2.y ^ (tg)) | (chv2.z ^ (tg)) | (chv2.w ^ (tg)) |      \
     (chv3.x ^ (tg)) | (chv3.y ^ (tg)) | (chv3.z ^ (tg)) | (chv3.w ^ (tg)) |      \
     (chv4.x ^ (tg)) | (chv4.y ^ (tg)) | (chv4.z ^ (tg)) | (chv4.w ^ (tg)) |      \
     (chv5.x ^ (tg)) | (chv5.y ^ (tg)) | (chv5.z ^ (tg)) | (chv5.w ^ (tg)) |      \
     (chv6.x ^ (tg)) | (chv6.y ^ (tg)) | (chv6.z ^ (tg)) | (chv6.w ^ (tg)) |      \
     (chv7.x ^ (tg)) | (chv7.y ^ (tg)) | (chv7.z ^ (tg)) | (chv7.w ^ (tg))) &     \
    0xFFFFu))

#define UNPACK_ROW(C, GG)                                                         \
  {                                                                               \
    unsigned lo = (chv##C.x >> 16) | (chv##C.y & 0xFFFF0000u);                    \
    unsigned hi = (chv##C.z >> 16) | (chv##C.w & 0xFFFF0000u);                    \
    uint2 pk2; pk2.x = lo; pk2.y = hi;                                            \
    *reinterpret_cast<uint2*>(&lds_h[((GG) * 8 + (C)) * HP + 4 * li]) = pk2;      \
  }

#define ISSUE_W(DST, trow)                                                        \
  {                                                                               \
    const float* ws_ = w + (size_t)(trow) * G_ + wgt * H_ + j0 + wc2;             \
    asm volatile("global_load_dwordx2 %0, %1, off nt"                             \
                 : "=&v"(DST) : "v"(ws_) : "memory");                             \
  }

  // ---- init ----
  if (!loader) {
    hreg0 = h0[col];
    hreg1 = hreg0;
    __bf16 hb = (__bf16)hreg0;
    unsigned pk = ((unsigned)*reinterpret_cast<u16*>(&hb) << 16) | 1u;
    unsigned* p0 = hbuf + (0 * 8 + bl) * H_ + col;
    unsigned* p1 = hbuf + (8 + bl) * H_ + col;
    asm volatile("global_store_dword %0, %2, off sc0 sc1\n\t"
                 "global_store_dword %1, %2, off sc0 sc1"
                 :: "v"(p0), "v"(p1), "v"(pk) : "memory");
  } else {
    // issue order matters for counted vmcnt: w(phase0) oldest, then bundle(phase0)
    ISSUE_W(wnxA, 0 * 16 + 0 * 8 + wb);   // w for (t=0, G=0)
    const unsigned* nb = hbuf + 4 * li;   // bundle (t=0, G=0)
    LOADB("sc0", nb);
  }

#define PHASE(GG, HREG, WCUR, WNXT)                                               \
  {                                                                               \
    const unsigned tag = (unsigned)(t + 1);                                       \
    const int tn = (GG == 0) ? t : ((t + 1 < T_) ? (t + 1) : t);                  \
    const int gn = GG ^ 1;                                                        \
    if (loader) {                                                                 \
      /* issue NEXT phase's w first: full phase of flight before its drain */     \
      ISSUE_W(WNXT, tn * 16 + gn * 8 + wb);                                       \
      /* counted wait: drains w_cur + bundle_cur (9 oldest), leaves w_next */     \
      asm volatile("s_waitcnt vmcnt(1)"                                           \
                   : "+v"(chv0), "+v"(chv1), "+v"(chv2), "+v"(chv3),              \
                     "+v"(chv4), "+v"(chv5), "+v"(chv6), "+v"(chv7),              \
                     "+v"(WCUR) :: "memory");                                     \
      __builtin_amdgcn_sched_barrier(0);                                          \
      unsigned bad = TAGCHK(tag);                                                 \
      if (bad) {                                                                  \
        const unsigned* cb = hbuf + (size_t)(t & 1) * BH + (GG) * 8192 + 4 * li;  \
        unsigned rounds = 0;                                                      \
        do {                                                                      \
          if (rounds == 0) {                                                      \
            LOADB("sc0", cb);                                                     \
          } else {                                                                \
            LOADB("sc0 sc1", cb);                                                 \
          }                                                                       \
          asm volatile("s_waitcnt vmcnt(0)"                                       \
                       : "+v"(chv0), "+v"(chv1), "+v"(chv2), "+v"(chv3),          \
                         "+v"(chv4), "+v"(chv5), "+v"(chv6), "+v"(chv7)           \
                       :: "memory");                                              \
          bad = TAGCHK(tag);                                                      \
        } while (bad && ++rounds < 4096u);                                        \
      }                                                                           \
      UNPACK_ROW(0, GG) UNPACK_ROW(1, GG) UNPACK_ROW(2, GG) UNPACK_ROW(3, GG)     \
      UNPACK_ROW(4, GG) UNPACK_ROW(5, GG) UNPACK_ROW(6, GG) UNPACK_ROW(7, GG)     \
      *reinterpret_cast<uint2*>(&lds_w[GG][wb][wgt][wc2]) = WCUR;                 \
      asm volatile("s_waitcnt lgkmcnt(0)" ::: "memory");                          \
    }                                                                             \
    __builtin_amdgcn_s_barrier(); /* (A) staging complete */                      \
    __builtin_amdgcn_sched_barrier(0);                                            \
    if (loader) {                                                                 \
      /* EARLY ISSUE: spec bundle for NEXT phase, pre-MFMA -> RT hides under      \
         MFMA + barrier B + update (data published >= 1 phase ago) */             \
      const unsigned* nb = hbuf + (size_t)(tn & 1) * BH + gn * 8192 + 4 * li;     \
      LOADB("sc0", nb);                                                           \
    }                                                                             \
    __builtin_amdgcn_sched_barrier(0);                                            \
    floatx4 acc0 = {0, 0, 0, 0}, acc1 = {0, 0, 0, 0};                             \
    {                                                                             \
      /* BROADCAST DEDUP: row GG*8+(am&7); lanes am/am+8 read same address */     \
      const u16* hb = &lds_h[((GG) * 8 + (am & 7)) * HP + kh * 512 + kq * 8];     \
      _Pragma("unroll")                                                           \
      for (int kk = 0; kk < 8; ++kk) {                                            \
        bf16x8 x0 = *reinterpret_cast<const bf16x8*>(hb + (kk + 0) * 32);         \
        bf16x8 x1 = *reinterpret_cast<const bf16x8*>(hb + (kk + 8) * 32);         \
        acc0 = __builtin_amdgcn_mfma_f32_16x16x32_bf16(x0, uf[kk + 0], acc0, 0, 0, 0); \
        acc1 = __builtin_amdgcn_mfma_f32_16x16x32_bf16(x1, uf[kk + 8], acc1, 0, 0, 0); \
      }                                                                           \
    }                                                                             \
    floatx4 acc = acc0 + acc1;                                                    \
    _Pragma("unroll")                                                             \
    for (int i = 0; i < 4; ++i)                                                   \
      lds_r[jt][kh][kq * 4 + i][am] = acc[i];                                     \
    asm volatile("s_waitcnt lgkmcnt(0)" ::: "memory");                            \
    __builtin_amdgcn_s_barrier(); /* (B) partials complete */                     \
    __builtin_amdgcn_sched_barrier(0);                                            \
    if (!loader) {                                                                \
      const int tl = jj >> 3, cc = jj & 7;                                        \
      const int mr = (GG) * 8 + bl;                                               \
      float a = lds_r[tl][0][mr][cc] + lds_r[tl][1][mr][cc] +                     \
                lds_w[GG][bl][0][jj];                                             \
      float z = lds_r[tl][0][mr][8 + cc] + lds_r[tl][1][mr][8 + cc] +             \
                lds_w[GG][bl][1][jj];                                             \
      float zs = 1.f / (1.f + __expf(-z));                                        \
      float hn = zs * (HREG) + (1.f - zs) * fmaxf(a, 0.f);                        \
      (HREG) = hn;                                                                \
      __bf16 hb16 = (__bf16)hn;                                                   \
      unsigned pk = ((unsigned)*reinterpret_cast<u16*>(&hb16) << 16) | (tag + 1u);\
      unsigned* pp = hbuf + (size_t)((t + 1) & 1) * BH + ((GG) * 8 + bl) * H_ + col; \
      asm volatile("global_store_dword %0, %1, off sc0 sc1"                       \
                   :: "v"(pp), "v"(pk) : "memory");                               \
      __builtin_nontemporal_store(hn, &out[((size_t)((GG) * 8 + bl) * T_ + t) * H_ + col]); \
    }                                                                             \
  }

#pragma unroll 1
  for (int t = 0; t < T_; ++t) {
    PHASE(0, hreg0, wnxA, wnxB)
    PHASE(1, hreg1, wnxB, wnxA)
  }
#undef PHASE
#undef LOADB
#undef TAGCHK
#undef UNPACK_ROW
#undef ISSUE_W
}

// ---------------- host ----------------
extern "C" void kernel_launch(void* const* d_in, const int* in_sizes, int n_in,
                              void* d_out, int out_size, void* d_ws, size_t ws_size,
                              hipStream_t stream) {
  (void)in_sizes; (void)n_in; (void)out_size; (void)ws_size;
  const float* x = (const float*)d_in[0];
  const float* Ww = (const float*)d_in[1];
  const float* Uw = (const float*)d_in[2];
  const float* gamma = (const float*)d_in[3];
  const float* beta = (const float*)d_in[4];
  const float* h0 = (const float*)d_in[5];
  float* out = (float*)d_out;

  char* p = (char*)d_ws;
  u16* xb = (u16*)p;      p += (size_t)8192 * 512 * 2;   // 8 MB
  u16* Wb = (u16*)p;      p += (size_t)2048 * 512 * 2;   // 2 MB
  u16* Ub = (u16*)p;      p += (size_t)2048 * 1024 * 2;  // 4 MB
  float* w = (float*)p;   p += (size_t)8192 * 2048 * 4;  // 64 MB  [T][B][G]
  unsigned* hbuf = (unsigned*)p; p += (size_t)2 * BH * 4; // 128 KB tagged dwords
  unsigned* elect = (unsigned*)p; p += 64;                // election state

  // tag 0 != any real tag; election counters + winner zeroed (contiguous)
  hipMemsetAsync(hbuf, 0, (size_t)2 * BH * 4 + 64, stream);
  cast_f32_bf16<<<512, 256, 0, stream>>>(x, xb, 8192 * 512);
  cast_f32_bf16<<<256, 256, 0, stream>>>(Ww, Wb, 2048 * 512);
  cast_f32_bf16<<<256, 256, 0, stream>>>(Uw, Ub, 2048 * 1024);
  gemm_xW<<<512, 256, 0, stream>>>(xb, Wb, w);
  layernorm_rows<<<8192, 256, 0, stream>>>(w, gamma, beta);

  const float* wc = w;
  const u16* Ubc = Ub;
  void* args[6] = { (void*)&wc, (void*)&Ubc, (void*)&h0, (void*)&out,
                    (void*)&hbuf, (void*)&elect };
  hipLaunchCooperativeKernel((void*)ligru_scan, dim3(256), dim3(512), args, 0, stream);
}

// Round 10
// 1676.083 us; speedup vs baseline: 2.8560x; 1.0076x over previous
//
#include <hip/hip_runtime.h>
#include <hip/hip_cooperative_groups.h>
#include <cmath>

typedef __bf16 bf16x8 __attribute__((ext_vector_type(8)));
typedef float floatx4 __attribute__((ext_vector_type(4)));
typedef unsigned ux4 __attribute__((ext_vector_type(4)));
typedef unsigned short u16;

#define B_ 16
#define T_ 512
#define D_ 512
#define H_ 1024
#define G_ 2048  // 2H
#define BH (B_ * H_)
#define HP 1032  // pitch u16 = 2064 B = 129*16B. MUST stay a multiple of 8 u16:
                 // non-16B-multiple pitches misalign ds_read_b128 on odd rows ->
                 // HW splits them -> 3x regression (R5/R6/R7 confound).

// ---------------- cast fp32 -> bf16 (RNE) ----------------
__global__ void cast_f32_bf16(const float* __restrict__ src, u16* __restrict__ dst, int n) {
  int i = blockIdx.x * blockDim.x + threadIdx.x;
  int stride = gridDim.x * blockDim.x;
  for (; i < n; i += stride) {
    __bf16 b = (__bf16)src[i];
    dst[i] = *reinterpret_cast<u16*>(&b);
  }
}

// ---------------- w = x @ W^T  (bf16 MFMA, fp32 out), layout w[t][b][2H] ----------------
__launch_bounds__(256, 1)
__global__ void gemm_xW(const u16* __restrict__ xb, const u16* __restrict__ Wb,
                        float* __restrict__ w) {
  const int lane = threadIdx.x & 63;
  const int wv = threadIdx.x >> 6;
  const int rt0 = blockIdx.x * 16;
  const int bidx = rt0 >> 9;
  const int t0 = rt0 & 511;
  const int am = lane & 15;
  const int kq = lane >> 4;

  bf16x8 af[16];
  {
    const u16* xrow = xb + (size_t)(rt0 + am) * D_ + kq * 8;
#pragma unroll
    for (int kk = 0; kk < 16; ++kk)
      af[kk] = *reinterpret_cast<const bf16x8*>(xrow + kk * 32);
  }

#pragma unroll 1
  for (int nt = 0; nt < 32; ++nt) {
    const int n0 = wv * 512 + nt * 16;
    floatx4 acc = {0.f, 0.f, 0.f, 0.f};
    const u16* wrow = Wb + (size_t)(n0 + am) * D_ + kq * 8;
#pragma unroll
    for (int kk = 0; kk < 16; ++kk) {
      bf16x8 bfr = *reinterpret_cast<const bf16x8*>(wrow + kk * 32);
      acc = __builtin_amdgcn_mfma_f32_16x16x32_bf16(af[kk], bfr, acc, 0, 0, 0);
    }
#pragma unroll
    for (int i = 0; i < 4; ++i) {
      int m = kq * 4 + i;
      w[(size_t)((t0 + m) * 16 + bidx) * G_ + n0 + am] = acc[i];
    }
  }
}

// ---------------- in-place LayerNorm over rows of 2048 ----------------
__launch_bounds__(256, 1)
__global__ void layernorm_rows(float* __restrict__ w, const float* __restrict__ gamma,
                               const float* __restrict__ beta) {
  float* r = w + (size_t)blockIdx.x * G_;
  float v[8];
  float s = 0.f, ss = 0.f;
#pragma unroll
  for (int i = 0; i < 8; ++i) {
    v[i] = r[threadIdx.x + i * 256];
    s += v[i];
    ss += v[i] * v[i];
  }
#pragma unroll
  for (int d = 1; d < 64; d <<= 1) {
    s += __shfl_xor(s, d, 64);
    ss += __shfl_xor(ss, d, 64);
  }
  __shared__ float ls[4], lss[4];
  const int wv = threadIdx.x >> 6;
  if ((threadIdx.x & 63) == 0) { ls[wv] = s; lss[wv] = ss; }
  __syncthreads();
  float S = ls[0] + ls[1] + ls[2] + ls[3];
  float SS = lss[0] + lss[1] + lss[2] + lss[3];
  float mu = S * (1.f / 2048.f);
  float var = SS * (1.f / 2048.f) - mu * mu;
  float rs = rsqrtf(var + 1e-5f);
#pragma unroll
  for (int i = 0; i < 8; ++i) {
    int g = threadIdx.x + i * 256;
    r[g] = (v[i] - mu) * rs * gamma[g] + beta[g];
  }
}

// ---------------- persistent LiGRU scan: R9 + K-quartered wave partition ----------
// R9 evidence: ds_read_b128 is ISSUE-limited (~12cy/instr); broadcast dedup of the
// data was null. The A-operand depends only on kk, yet the old (4 n-tile x 2
// K-half) wave partition made 4 waves re-read the same K-half: 128 A-read instrs
// per CU per phase (~0.61us, dominant term).
// R10: waves partitioned as (2 n-tiles x K-quarter). Each wave: 8 ds_read_b128
// (its K-quarter) feeding 16 MFMAs (both tiles of its pair). A-read instrs halve
// to 64/CU/phase. lds_r gains a quarter axis [4][4][17][17]; update sums 4
// partials. Exchange protocol byte-identical to R9 (role split + XCD election +
// sc0 spec bundles + escalating retry + early issue + counted vmcnt(1)).
__launch_bounds__(512, 1)
__global__ void ligru_scan(const float* __restrict__ w, const u16* __restrict__ Ub,
                           const float* __restrict__ h0, float* __restrict__ out,
                           unsigned* __restrict__ hbuf, unsigned* __restrict__ elect) {
  // ---- election: claim a slot on my XCD; first XCD to 32 slots wins ----
  __shared__ unsigned s_role;
  if (threadIdx.x == 0) {
    unsigned xcc;
    asm volatile("s_getreg_b32 %0, hwreg(HW_REG_XCC_ID)" : "=s"(xcc));
    xcc &= 7u;
    unsigned ticket = atomicAdd(&elect[xcc], 1u);
    if (ticket == 31u) atomicCAS(&elect[8], 0u, xcc + 1u);
    unsigned wn;
    while ((wn = atomicAdd(&elect[8], 0u)) == 0u) __builtin_amdgcn_s_sleep(8);
    s_role = (wn == xcc + 1u && ticket < 32u) ? ticket : 0xFFFFFFFFu;
  }
  __syncthreads();
  const unsigned role = s_role;
  if (role == 0xFFFFFFFFu) return;  // not a worker

  const int tid = threadIdx.x;
  const int lane = tid & 63;
  const int wv = tid >> 6;
  const int am = lane & 15;
  const int kq = lane >> 4;
  const int j0 = (int)role * 32;
  const bool loader = (tid >= 256);
  const int tA = 2 * (wv & 1);     // tile pair base: tiles tA, tA+1
  const int kq4 = wv >> 1;         // K quarter 0..3 (updaters 0-1, loaders 2-3)

  __shared__ u16 lds_h[16 * HP];          // rows g*8..g*8+7 = group g h (bf16 bits)
  __shared__ float lds_r[4][4][17][17];   // [tile][K-quarter][m-row][n-col] padded
  __shared__ float lds_w[2][8][2][32];    // [group][batch][gate][col] staged w_t

  // U fragments: 2 tiles x 8 kk of this wave's K-quarter, register resident
  bf16x8 uf0[8], uf1[8];
  {
    const int growA = (am < 8) ? (j0 + 8 * tA + am) : (H_ + j0 + 8 * tA + (am - 8));
    const int growB = (am < 8) ? (j0 + 8 * (tA + 1) + am)
                               : (H_ + j0 + 8 * (tA + 1) + (am - 8));
    const u16* urowA = Ub + (size_t)growA * H_ + kq4 * 256 + kq * 8;
    const u16* urowB = Ub + (size_t)growB * H_ + kq4 * 256 + kq * 8;
#pragma unroll
    for (int kk = 0; kk < 8; ++kk) {
      uf0[kk] = *reinterpret_cast<const bf16x8*>(urowA + kk * 32);
      uf1[kk] = *reinterpret_cast<const bf16x8*>(urowB + kk * 32);
    }
  }

  // updater mapping: thread owns (batch bl of each group, col jj)
  const int bl = tid >> 5;   // 0..7 for updaters
  const int jj = tid & 31;
  const int col = j0 + jj;
  float hreg0 = 0.f, hreg1 = 0.f;

  // loader mapping
  const int li = tid & 255;        // 0..255
  const int wb = li >> 5;          // w batch-local
  const int wgt = (li >> 4) & 1;   // w gate
  const int wc2 = (li & 15) * 2;   // w col pair
  ux4 chv0, chv1, chv2, chv3, chv4, chv5, chv6, chv7;
  uint2 wnxA, wnxB;                // w ping-pong (A = G0 phases, B = G1)

#define LOADB(SCSTR, cb)                                                          \
  asm volatile("global_load_dwordx4 %0, %8, off " SCSTR "\n\t"                    \
               "global_load_dwordx4 %1, %9, off " SCSTR "\n\t"                    \
               "global_load_dwordx4 %2, %10, off " SCSTR "\n\t"                   \
               "global_load_dwordx4 %3, %11, off " SCSTR "\n\t"                   \
               "global_load_dwordx4 %4, %12, off " SCSTR "\n\t"                   \
               "global_load_dwordx4 %5, %13, off " SCSTR "\n\t"                   \
               "global_load_dwordx4 %6, %14, off " SCSTR "\n\t"                   \
               "global_load_dwordx4 %7, %15, off " SCSTR                          \
               : "=&v"(chv0), "=&v"(chv1), "=&v"(chv2), "=&v"(chv3),              \
                 "=&v"(chv4), "=&v"(chv5), "=&v"(chv6), "=&v"(chv7)               \
               : "v"(cb), "v"((cb) + 1024), "v"((cb) + 2048), "v"((cb) + 3072),   \
                 "v"((cb) + 4096), "v"((cb) + 5120), "v"((cb) + 6144),            \
                 "v"((cb) + 7168)                                                 \
               : "memory")

#define TAGCHK(tg)                                                                \
  ((((chv0.x ^ (tg)) | (chv0.y ^ (tg)) | (chv0.z ^ (tg)) | (chv0.w ^ (tg)) |      \
     (chv1.x ^ (tg)) | (chv1.y ^ (tg)) | (chv1.z ^ (tg)) | (chv1.w ^ (tg)) |      \
     (chv2.x ^ (tg)) | (chv2.y ^ (tg)) | (chv2.z ^ (tg)) | (chv2.w ^ (tg)) |      \
     (chv3.x ^ (tg)) | (chv3.y ^ (tg)) | (chv3.z ^ (tg)) | (chv3.w ^ (tg)) |      \
     (chv4.x ^ (tg)) | (chv4.y ^ (tg)) | (chv4.z ^ (tg)) | (chv4.w ^ (tg)) |      \
     (chv5.x ^ (tg)) | (chv5.y ^ (tg)) | (chv5.z ^ (tg)) | (chv5.w ^ (tg)) |      \
     (chv6.x ^ (tg)) | (chv6.y ^ (tg)) | (chv6.z ^ (tg)) | (chv6.w ^ (tg)) |      \
     (chv7.x ^ (tg)) | (chv7.y ^ (tg)) | (chv7.z ^ (tg)) | (chv7.w ^ (tg))) &     \
    0xFFFFu))

#define UNPACK_ROW(C, GG)                                                         \
  {                                                                               \
    unsigned lo = (chv##C.x >> 16) | (chv##C.y & 0xFFFF0000u);                    \
    unsigned hi = (chv##C.z >> 16) | (chv##C.w & 0xFFFF0000u);                    \
    uint2 pk2; pk2.x = lo; pk2.y = hi;                                            \
    *reinterpret_cast<uint2*>(&lds_h[((GG) * 8 + (C)) * HP + 4 * li]) = pk2;      \
  }

#define ISSUE_W(DST, trow)                                                        \
  {                                                                               \
    const float* ws_ = w + (size_t)(trow) * G_ + wgt * H_ + j0 + wc2;             \
    asm volatile("global_load_dwordx2 %0, %1, off nt"                             \
                 : "=&v"(DST) : "v"(ws_) : "memory");                             \
  }

  // ---- init ----
  if (!loader) {
    hreg0 = h0[col];
    hreg1 = hreg0;
    __bf16 hb = (__bf16)hreg0;
    unsigned pk = ((unsigned)*reinterpret_cast<u16*>(&hb) << 16) | 1u;
    unsigned* p0 = hbuf + (0 * 8 + bl) * H_ + col;
    unsigned* p1 = hbuf + (8 + bl) * H_ + col;
    asm volatile("global_store_dword %0, %2, off sc0 sc1\n\t"
                 "global_store_dword %1, %2, off sc0 sc1"
                 :: "v"(p0), "v"(p1), "v"(pk) : "memory");
  } else {
    // issue order matters for counted vmcnt: w(phase0) oldest, then bundle(phase0)
    ISSUE_W(wnxA, 0 * 16 + 0 * 8 + wb);   // w for (t=0, G=0)
    const unsigned* nb = hbuf + 4 * li;   // bundle (t=0, G=0)
    LOADB("sc0", nb);
  }

#define PHASE(GG, HREG, WCUR, WNXT)                                               \
  {                                                                               \
    const unsigned tag = (unsigned)(t + 1);                                       \
    const int tn = (GG == 0) ? t : ((t + 1 < T_) ? (t + 1) : t);                  \
    const int gn = GG ^ 1;                                                        \
    if (loader) {                                                                 \
      /* issue NEXT phase's w first: full phase of flight before its drain */     \
      ISSUE_W(WNXT, tn * 16 + gn * 8 + wb);                                       \
      /* counted wait: drains w_cur + bundle_cur (9 oldest), leaves w_next */     \
      asm volatile("s_waitcnt vmcnt(1)"                                           \
                   : "+v"(chv0), "+v"(chv1), "+v"(chv2), "+v"(chv3),              \
                     "+v"(chv4), "+v"(chv5), "+v"(chv6), "+v"(chv7),              \
                     "+v"(WCUR) :: "memory");                                     \
      __builtin_amdgcn_sched_barrier(0);                                          \
      unsigned bad = TAGCHK(tag);                                                 \
      if (bad) {                                                                  \
        const unsigned* cb = hbuf + (size_t)(t & 1) * BH + (GG) * 8192 + 4 * li;  \
        unsigned rounds = 0;                                                      \
        do {                                                                      \
          if (rounds == 0) {                                                      \
            LOADB("sc0", cb);                                                     \
          } else {                                                                \
            LOADB("sc0 sc1", cb);                                                 \
          }                                                                       \
          asm volatile("s_waitcnt vmcnt(0)"                                       \
                       : "+v"(chv0), "+v"(chv1), "+v"(chv2), "+v"(chv3),          \
                         "+v"(chv4), "+v"(chv5), "+v"(chv6), "+v"(chv7)           \
                       :: "memory");                                              \
          bad = TAGCHK(tag);                                                      \
        } while (bad && ++rounds < 4096u);                                        \
      }                                                                           \
      UNPACK_ROW(0, GG) UNPACK_ROW(1, GG) UNPACK_ROW(2, GG) UNPACK_ROW(3, GG)     \
      UNPACK_ROW(4, GG) UNPACK_ROW(5, GG) UNPACK_ROW(6, GG) UNPACK_ROW(7, GG)     \
      *reinterpret_cast<uint2*>(&lds_w[GG][wb][wgt][wc2]) = WCUR;                 \
      asm volatile("s_waitcnt lgkmcnt(0)" ::: "memory");                          \
    }                                                                             \
    __builtin_amdgcn_s_barrier(); /* (A) staging complete */                      \
    __builtin_amdgcn_sched_barrier(0);                                            \
    if (loader) {                                                                 \
      /* EARLY ISSUE: spec bundle for NEXT phase, pre-MFMA -> RT hides under      \
         MFMA + barrier B + update (data published >= 1 phase ago) */             \
      const unsigned* nb = hbuf + (size_t)(tn & 1) * BH + gn * 8192 + 4 * li;     \
      LOADB("sc0", nb);                                                           \
    }                                                                             \
    __builtin_amdgcn_sched_barrier(0);                                            \
    floatx4 accA = {0, 0, 0, 0}, accB = {0, 0, 0, 0};                             \
    {                                                                             \
      /* one A-read (K-quarter) feeds BOTH tiles of the pair */                   \
      const u16* hb = &lds_h[((GG) * 8 + (am & 7)) * HP + kq4 * 256 + kq * 8];    \
      _Pragma("unroll")                                                           \
      for (int kk = 0; kk < 8; ++kk) {                                            \
        bf16x8 x = *reinterpret_cast<const bf16x8*>(hb + kk * 32);                \
        accA = __builtin_amdgcn_mfma_f32_16x16x32_bf16(x, uf0[kk], accA, 0, 0, 0);\
        accB = __builtin_amdgcn_mfma_f32_16x16x32_bf16(x, uf1[kk], accB, 0, 0, 0);\
      }                                                                           \
    }                                                                             \
    _Pragma("unroll")                                                             \
    for (int i = 0; i < 4; ++i) {                                                 \
      lds_r[tA][kq4][kq * 4 + i][am] = accA[i];                                   \
      lds_r[tA + 1][kq4][kq * 4 + i][am] = accB[i];                               \
    }                                                                             \
    asm volatile("s_waitcnt lgkmcnt(0)" ::: "memory");                            \
    __builtin_amdgcn_s_barrier(); /* (B) partials complete */                     \
    __builtin_amdgcn_sched_barrier(0);                                            \
    if (!loader) {                                                                \
      const int tl = jj >> 3, cc = jj & 7;                                        \
      const int mr = (GG) * 8 + bl;                                               \
      float a = (lds_r[tl][0][mr][cc] + lds_r[tl][1][mr][cc]) +                   \
                (lds_r[tl][2][mr][cc] + lds_r[tl][3][mr][cc]) +                   \
                lds_w[GG][bl][0][jj];                                             \
      float z = (lds_r[tl][0][mr][8 + cc] + lds_r[tl][1][mr][8 + cc]) +           \
                (lds_r[tl][2][mr][8 + cc] + lds_r[tl][3][mr][8 + cc]) +           \
                lds_w[GG][bl][1][jj];                                             \
      float zs = 1.f / (1.f + __expf(-z));                                        \
      float hn = zs * (HREG) + (1.f - zs) * fmaxf(a, 0.f);                        \
      (HREG) = hn;                                                                \
      __bf16 hb16 = (__bf16)hn;                                                   \
      unsigned pk = ((unsigned)*reinterpret_cast<u16*>(&hb16) << 16) | (tag + 1u);\
      unsigned* pp = hbuf + (size_t)((t + 1) & 1) * BH + ((GG) * 8 + bl) * H_ + col; \
      asm volatile("global_store_dword %0, %1, off sc0 sc1"                       \
                   :: "v"(pp), "v"(pk) : "memory");                               \
      __builtin_nontemporal_store(hn, &out[((size_t)((GG) * 8 + bl) * T_ + t) * H_ + col]); \
    }                                                                             \
  }

#pragma unroll 1
  for (int t = 0; t < T_; ++t) {
    PHASE(0, hreg0, wnxA, wnxB)
    PHASE(1, hreg1, wnxB, wnxA)
  }
#undef PHASE
#undef LOADB
#undef TAGCHK
#undef UNPACK_ROW
#undef ISSUE_W
}

// ---------------- host ----------------
extern "C" void kernel_launch(void* const* d_in, const int* in_sizes, int n_in,
                              void* d_out, int out_size, void* d_ws, size_t ws_size,
                              hipStream_t stream) {
  (void)in_sizes; (void)n_in; (void)out_size; (void)ws_size;
  const float* x = (const float*)d_in[0];
  const float* Ww = (const float*)d_in[1];
  const float* Uw = (const float*)d_in[2];
  const float* gamma = (const float*)d_in[3];
  const float* beta = (const float*)d_in[4];
  const float* h0 = (const float*)d_in[5];
  float* out = (float*)d_out;

  char* p = (char*)d_ws;
  u16* xb = (u16*)p;      p += (size_t)8192 * 512 * 2;   // 8 MB
  u16* Wb = (u16*)p;      p += (size_t)2048 * 512 * 2;   // 2 MB
  u16* Ub = (u16*)p;      p += (size_t)2048 * 1024 * 2;  // 4 MB
  float* w = (float*)p;   p += (size_t)8192 * 2048 * 4;  // 64 MB  [T][B][G]
  unsigned* hbuf = (unsigned*)p; p += (size_t)2 * BH * 4; // 128 KB tagged dwords
  unsigned* elect = (unsigned*)p; p += 64;                // election state

  // tag 0 != any real tag; election counters + winner zeroed (contiguous)
  hipMemsetAsync(hbuf, 0, (size_t)2 * BH * 4 + 64, stream);
  cast_f32_bf16<<<512, 256, 0, stream>>>(x, xb, 8192 * 512);
  cast_f32_bf16<<<256, 256, 0, stream>>>(Ww, Wb, 2048 * 512);
  cast_f32_bf16<<<256, 256, 0, stream>>>(Uw, Ub, 2048 * 1024);
  gemm_xW<<<512, 256, 0, stream>>>(xb, Wb, w);
  layernorm_rows<<<8192, 256, 0, stream>>>(w, gamma, beta);

  const float* wc = w;
  const u16* Ubc = Ub;
  void* args[6] = { (void*)&wc, (void*)&Ubc, (void*)&h0, (void*)&out,
                    (void*)&hbuf, (void*)&elect };
  hipLaunchCooperativeKernel((void*)ligru_scan, dim3(256), dim3(512), args, 0, stream);
}